// Round 1
// baseline (1597.977 us; speedup 1.0000x reference)
//
#include <hip/hip_runtime.h>
#include <math.h>

#define BQ 2048
#define BN 65536
#define HDIM 256
#define TOPK 7
#define PSPLIT 8
#define QT 32
#define NT 256
#define NTILES (BN / PSPLIT / NT)   /* 32 */
#define PPAD 20                     /* padded LDS row stride in floats */

__device__ __forceinline__ bool lexgt(float v1, int i1, float v2, int i2) {
    // true if (v1,i1) ranks strictly ahead of (v2,i2): value desc, index asc
    return (v1 > v2) || (v1 == v2 && i1 < i2);
}

// ---------------- prep: row inverse norms (1 wave per row, 4 rows/block) ----
__global__ void row_norms(const float* __restrict__ x, float* __restrict__ inv, int rows) {
    int wid = threadIdx.x >> 6, lane = threadIdx.x & 63;
    int row = blockIdx.x * 4 + wid;
    if (row >= rows) return;
    float4 v = *(const float4*)&x[(size_t)row * HDIM + lane * 4];
    float s = v.x * v.x + v.y * v.y + v.z * v.z + v.w * v.w;
    #pragma unroll
    for (int off = 32; off >= 1; off >>= 1) s += __shfl_xor(s, off);
    if (lane == 0) inv[row] = 1.0f / fmaxf(sqrtf(s), 1e-12f);
}

// ---------------- prep: global min of pool_time -----------------------------
__global__ void time_min_kernel(const float* __restrict__ t, unsigned* __restrict__ m, int n) {
    float mn = 3.0e38f;
    for (int i = blockIdx.x * blockDim.x + threadIdx.x; i < n; i += gridDim.x * blockDim.x)
        mn = fminf(mn, t[i]);
    #pragma unroll
    for (int off = 32; off >= 1; off >>= 1) mn = fminf(mn, __shfl_xor(mn, off));
    __shared__ float wmin[4];
    int wid = threadIdx.x >> 6, lane = threadIdx.x & 63;
    if (lane == 0) wmin[wid] = mn;
    __syncthreads();
    if (threadIdx.x == 0) {
        float b = fminf(fminf(wmin[0], wmin[1]), fminf(wmin[2], wmin[3]));
        atomicMin(m, __float_as_uint(b));   // nonneg floats: uint order == float order
    }
}

// ---------------- main: tiled sims + fused running top-7 --------------------
__global__ __launch_bounds__(512, 2) void sim_topk_kernel(
    const float* __restrict__ pool_emb, const float* __restrict__ pool_time,
    const float* __restrict__ query_emb, const float* __restrict__ query_time,
    const float* __restrict__ inv_pn, const float* __restrict__ inv_qn,
    const unsigned* __restrict__ minpt,
    float* __restrict__ pv, int* __restrict__ pi)
{
    __shared__ __align__(16) float q_s[QT][HDIM];       // 32 KB
    __shared__ __align__(16) float p_s[2][NT][PPAD];    // 40 KB

    const int tid = threadIdx.x;
    const int ty = tid >> 6;       // 0..7 (wave id)
    const int tx = tid & 63;       // lane
    const int split = blockIdx.x & 7;
    const int qb = blockIdx.x >> 3;
    const int qbase = qb * QT;

    // stage the 32 resident query rows (float4-coalesced)
    #pragma unroll
    for (int k = 0; k < 4; ++k) {
        int c = tid + k * 512;            // float4 chunk, 2048 total
        int row = c >> 6;
        int col = (c & 63) << 2;
        *(float4*)&q_s[row][col] = *(const float4*)&query_emb[(size_t)(qbase + row) * HDIM + col];
    }

    float tq[4], qiv[4], qep[4], qem[4];
    bool hv[4];
    float tv[4][TOPK];
    int tix[4][TOPK];
    const float mpt = __uint_as_float(*minpt);
    #pragma unroll
    for (int iq = 0; iq < 4; ++iq) {
        int q = qbase + ty * 4 + iq;
        tq[iq] = query_time[q];
        qiv[iq] = inv_qn[q];
        hv[iq] = (mpt < tq[iq]);
        qep[iq] = expf(0.1f * tq[iq]);
        qem[iq] = expf(-0.1f * tq[iq]);
        #pragma unroll
        for (int s = 0; s < TOPK; ++s) { tv[iq][s] = -INFINITY; tix[iq][s] = 0x7fffffff; }
    }

    auto stage = [&](int b, int pb, int hs) {
        #pragma unroll
        for (int k = 0; k < 2; ++k) {
            int c = tid * 2 + k;           // 1024 float4 chunks (256 rows x 4)
            int row = c >> 2;
            int c4 = c & 3;
            *(float4*)&p_s[b][row][c4 * 4] =
                *(const float4*)&pool_emb[(size_t)(pb + row) * HDIM + hs * 16 + c4 * 4];
        }
    };

    for (int t = 0; t < NTILES; ++t) {
        const int pb = split * (BN / PSPLIT) + t * NT;
        float acc[4][4];
        #pragma unroll
        for (int iq = 0; iq < 4; ++iq)
            #pragma unroll
            for (int jp = 0; jp < 4; ++jp) acc[iq][jp] = 0.0f;

        stage(0, pb, 0);
        __syncthreads();
        for (int hs = 0; hs < 16; ++hs) {
            if (hs < 15) stage((hs + 1) & 1, pb, hs + 1);
            const int b = hs & 1;
            #pragma unroll
            for (int c4 = 0; c4 < 4; ++c4) {
                float4 qf[4];
                #pragma unroll
                for (int iq = 0; iq < 4; ++iq)
                    qf[iq] = *(const float4*)&q_s[ty * 4 + iq][hs * 16 + c4 * 4];
                float4 pf[4];
                #pragma unroll
                for (int jp = 0; jp < 4; ++jp)
                    pf[jp] = *(const float4*)&p_s[b][tx + 64 * jp][c4 * 4];
                #pragma unroll
                for (int iq = 0; iq < 4; ++iq) {
                    #pragma unroll
                    for (int jp = 0; jp < 4; ++jp) {
                        acc[iq][jp] += qf[iq].x * pf[jp].x;
                        acc[iq][jp] += qf[iq].y * pf[jp].y;
                        acc[iq][jp] += qf[iq].z * pf[jp].z;
                        acc[iq][jp] += qf[iq].w * pf[jp].w;
                    }
                }
            }
            __syncthreads();
        }

        // epilogue: sim_t, causal mask, top-7 insertion
        #pragma unroll
        for (int jp = 0; jp < 4; ++jp) {
            int pj = pb + tx + 64 * jp;
            float tp = pool_time[pj];
            float piv = inv_pn[pj];
            float ep = expf(0.1f * tp), em = expf(-0.1f * tp);
            #pragma unroll
            for (int iq = 0; iq < 4; ++iq) {
                float decay = fminf(qem[iq] * ep, qep[iq] * em);  // == exp(-0.1*|dt|)
                float v = acc[iq][jp] * (qiv[iq] * piv) * decay;
                bool causal = tp < tq[iq];
                if (hv[iq] && !causal) v = -INFINITY;
                if (lexgt(v, pj, tv[iq][TOPK - 1], tix[iq][TOPK - 1])) {
                    tv[iq][TOPK - 1] = v; tix[iq][TOPK - 1] = pj;
                    #pragma unroll
                    for (int s = TOPK - 1; s > 0; --s) {
                        if (lexgt(tv[iq][s], tix[iq][s], tv[iq][s - 1], tix[iq][s - 1])) {
                            float fv = tv[iq][s]; tv[iq][s] = tv[iq][s - 1]; tv[iq][s - 1] = fv;
                            int ii = tix[iq][s]; tix[iq][s] = tix[iq][s - 1]; tix[iq][s - 1] = ii;
                        }
                    }
                }
            }
        }
    }

    // wave-level butterfly merge of sorted-7 lists (lex order)
    #define CE(a, b) { if (lexgt(tv[iq][b], tix[iq][b], tv[iq][a], tix[iq][a])) { \
        float fv = tv[iq][a]; tv[iq][a] = tv[iq][b]; tv[iq][b] = fv;              \
        int ii = tix[iq][a]; tix[iq][a] = tix[iq][b]; tix[iq][b] = ii; } }
    #pragma unroll
    for (int off = 1; off < 64; off <<= 1) {
        #pragma unroll
        for (int iq = 0; iq < 4; ++iq) {
            float ov[TOPK]; int oi[TOPK];
            #pragma unroll
            for (int s = 0; s < TOPK; ++s) {
                ov[s] = __shfl_xor(tv[iq][s], off);
                oi[s] = __shfl_xor(tix[iq][s], off);
            }
            // keep top-7 of the 14 (max stage of bitonic merge)
            #pragma unroll
            for (int i = 0; i < TOPK; ++i) {
                if (lexgt(ov[6 - i], oi[6 - i], tv[iq][i], tix[iq][i])) {
                    tv[iq][i] = ov[6 - i]; tix[iq][i] = oi[6 - i];
                }
            }
            // Batcher odd-even sorting network for 8, comparators with slot 7 (-inf sentinel) removed
            CE(0,1); CE(2,3); CE(4,5);
            CE(0,2); CE(1,3); CE(4,6);
            CE(1,2); CE(5,6);
            CE(0,4); CE(1,5); CE(2,6);
            CE(2,4); CE(3,5);
            CE(1,2); CE(3,4); CE(5,6);
        }
    }
    #undef CE

    if (tx == 0) {
        #pragma unroll
        for (int iq = 0; iq < 4; ++iq) {
            int q = qbase + ty * 4 + iq;
            #pragma unroll
            for (int s = 0; s < TOPK; ++s) {
                pv[(q * PSPLIT + split) * TOPK + s] = tv[iq][s];
                pi[(q * PSPLIT + split) * TOPK + s] = tix[iq][s];
            }
        }
    }
}

// ---------------- finalize: merge partials + attention fusion + score -------
__global__ __launch_bounds__(64) void finalize_kernel(
    const float* __restrict__ pool_emb, const float* __restrict__ query_emb,
    const float* __restrict__ pv, const int* __restrict__ pi,
    float* __restrict__ out)
{
    const int q = blockIdx.x;
    const int lane = threadIdx.x;

    float v = -INFINITY; int ix = 0x7fffffff;
    if (lane < PSPLIT * TOPK) {
        v = pv[q * PSPLIT * TOPK + lane];
        ix = pi[q * PSPLIT * TOPK + lane];
    }
    int ri[TOPK];
    #pragma unroll
    for (int k = 0; k < TOPK; ++k) {
        float mv = v; int mi = ix;
        #pragma unroll
        for (int off = 32; off >= 1; off >>= 1) {
            float v2 = __shfl_xor(mv, off);
            int i2 = __shfl_xor(mi, off);
            if (lexgt(v2, i2, mv, mi)) { mv = v2; mi = i2; }
        }
        ri[k] = mi;
        if (ix == mi) { v = -INFINITY; ix = 0x7fffffff; }  // knock out winner
    }

    const float4 qv = *(const float4*)&query_emb[(size_t)q * HDIM + lane * 4];
    float4 rk[TOPK];
    float lg[TOPK];
    #pragma unroll
    for (int k = 0; k < TOPK; ++k) {
        rk[k] = *(const float4*)&pool_emb[(size_t)ri[k] * HDIM + lane * 4];
        float d = qv.x * rk[k].x + qv.y * rk[k].y + qv.z * rk[k].z + qv.w * rk[k].w;
        #pragma unroll
        for (int off = 32; off >= 1; off >>= 1) d += __shfl_xor(d, off);
        lg[k] = d * 0.0625f;   // H^-0.5 = 1/16 exactly
    }
    float m = lg[0];
    #pragma unroll
    for (int k = 1; k < TOPK; ++k) m = fmaxf(m, lg[k]);
    float e[TOPK], se = 0.0f;
    #pragma unroll
    for (int k = 0; k < TOPK; ++k) { e[k] = expf(lg[k] - m); se += e[k]; }
    float inv_se = 1.0f / se;
    float4 f = make_float4(0.f, 0.f, 0.f, 0.f);
    #pragma unroll
    for (int k = 0; k < TOPK; ++k) {
        float a = e[k] * inv_se;
        f.x += a * rk[k].x; f.y += a * rk[k].y; f.z += a * rk[k].z; f.w += a * rk[k].w;
    }
    float dqf = qv.x * f.x + qv.y * f.y + qv.z * f.z + qv.w * f.w;
    float nq  = qv.x * qv.x + qv.y * qv.y + qv.z * qv.z + qv.w * qv.w;
    float nf  = f.x * f.x + f.y * f.y + f.z * f.z + f.w * f.w;
    float dx = qv.x - f.x, dy = qv.y - f.y, dz = qv.z - f.z, dw = qv.w - f.w;
    float d2 = dx * dx + dy * dy + dz * dz + dw * dw;
    #pragma unroll
    for (int off = 32; off >= 1; off >>= 1) {
        dqf += __shfl_xor(dqf, off);
        nq  += __shfl_xor(nq, off);
        nf  += __shfl_xor(nf, off);
        d2  += __shfl_xor(d2, off);
    }
    if (lane == 0) {
        float cosv = dqf / fmaxf(sqrtf(nq) * sqrtf(nf), 1e-8f);
        float l2 = sqrtf(d2);
        out[q] = 0.5f * (1.0f - cosv) + 0.5f * l2;
    }
}

extern "C" void kernel_launch(void* const* d_in, const int* in_sizes, int n_in,
                              void* d_out, int out_size, void* d_ws, size_t ws_size,
                              hipStream_t stream) {
    const float* query_emb  = (const float*)d_in[0];
    const float* query_time = (const float*)d_in[1];
    const float* pool_emb   = (const float*)d_in[2];
    const float* pool_time  = (const float*)d_in[3];
    float* out = (float*)d_out;

    float* inv_pn = (float*)d_ws;                 // BN
    float* inv_qn = inv_pn + BN;                  // BQ
    unsigned* minpt = (unsigned*)(inv_qn + BQ);   // 1 (padded to 4)
    float* pv = (float*)(minpt + 4);              // BQ*PSPLIT*TOPK
    int* pi = (int*)(pv + BQ * PSPLIT * TOPK);    // BQ*PSPLIT*TOPK

    hipMemsetAsync(minpt, 0x7F, 4, stream);       // 0x7F7F7F7F = big float
    row_norms<<<BN / 4, 256, 0, stream>>>(pool_emb, inv_pn, BN);
    row_norms<<<BQ / 4, 256, 0, stream>>>(query_emb, inv_qn, BQ);
    time_min_kernel<<<64, 256, 0, stream>>>(pool_time, minpt, BN);
    sim_topk_kernel<<<QT == 0 ? 0 : (BQ / QT) * PSPLIT, 512, 0, stream>>>(
        pool_emb, pool_time, query_emb, query_time, inv_pn, inv_qn, minpt, pv, pi);
    finalize_kernel<<<BQ, 64, 0, stream>>>(pool_emb, query_emb, pv, pi, out);
}

// Round 3
// 698.419 us; speedup vs baseline: 2.2880x; 2.2880x over previous
//
#include <hip/hip_runtime.h>
#include <math.h>

#define BQ 2048
#define BN 65536
#define HDIM 256
#define TOPK 7

// ---- new-path geometry ----
#define PB 128               // pool rows per block
#define NPB (BN / PB)        // 512 blocks
#define QI 256               // queries per iteration
#define NQI (BQ / QI)        // 8
#define BK 64                // K-chunk
#define NKC (HDIM / BK)      // 4
#define MINDECAY 0.904837f   // exp(-0.1*1)

// ---- old-path geometry (fallback) ----
#define PSPLIT 8
#define QT 32
#define NT 256
#define NTILES (BN / PSPLIT / NT)

typedef unsigned short u16;
using bf16x8 = __attribute__((ext_vector_type(8))) short;
using f32x16 = __attribute__((ext_vector_type(16))) float;

__device__ __forceinline__ bool lexgt(float v1, int i1, float v2, int i2) {
    // (v1,i1) strictly ahead of (v2,i2): value desc, index asc
    return (v1 > v2) || (v1 == v2 && i1 < i2);
}

__device__ __forceinline__ u16 f2bf(float f) {
    unsigned u = __float_as_uint(f);
    unsigned r = (u + 0x7fffu + ((u >> 16) & 1u)) >> 16;
    return (u16)r;
}

__device__ __forceinline__ void ce4(float& va, int& ia, float& vb, int& ib) {
    if (lexgt(vb, ib, va, ia)) {
        float t = va; va = vb; vb = t;
        int ti = ia; ia = ib; ib = ti;
    }
}
__device__ __forceinline__ void sort4(float (&V)[4], int (&I)[4]) {
    ce4(V[0], I[0], V[2], I[2]); ce4(V[1], I[1], V[3], I[3]);
    ce4(V[0], I[0], V[1], I[1]); ce4(V[2], I[2], V[3], I[3]);
}
__device__ __forceinline__ void merge_top4(float (&V)[4], int (&I)[4],
                                           const float (&W)[4], const int (&J)[4]) {
    #pragma unroll
    for (int s = 0; s < 4; ++s)
        if (lexgt(W[3 - s], J[3 - s], V[s], I[s])) { V[s] = W[3 - s]; I[s] = J[3 - s]; }
    sort4(V, I);
}

// ================= prep kernels =================
__global__ void row_norms(const float* __restrict__ x, float* __restrict__ inv, int rows) {
    int wid = threadIdx.x >> 6, lane = threadIdx.x & 63;
    int row = blockIdx.x * 4 + wid;
    if (row >= rows) return;
    float4 v = *(const float4*)&x[(size_t)row * HDIM + lane * 4];
    float s = v.x * v.x + v.y * v.y + v.z * v.z + v.w * v.w;
    #pragma unroll
    for (int off = 32; off >= 1; off >>= 1) s += __shfl_xor(s, off);
    if (lane == 0) inv[row] = 1.0f / fmaxf(sqrtf(s), 1e-12f);
}

__global__ void time_min_kernel(const float* __restrict__ t, unsigned* __restrict__ m, int n) {
    float mn = 3.0e38f;
    for (int i = blockIdx.x * blockDim.x + threadIdx.x; i < n; i += gridDim.x * blockDim.x)
        mn = fminf(mn, t[i]);
    #pragma unroll
    for (int off = 32; off >= 1; off >>= 1) mn = fminf(mn, __shfl_xor(mn, off));
    __shared__ float wmin[4];
    int wid = threadIdx.x >> 6, lane = threadIdx.x & 63;
    if (lane == 0) wmin[wid] = mn;
    __syncthreads();
    if (threadIdx.x == 0) {
        float b = fminf(fminf(wmin[0], wmin[1]), fminf(wmin[2], wmin[3]));
        atomicMin(m, __float_as_uint(b));
    }
}

// pool time table: (tp, e^{+0.1tp}, e^{-0.1tp}, 0)
__global__ void pprep_kernel(const float* __restrict__ pool_time, float4* __restrict__ ptab) {
    int p = blockIdx.x * blockDim.x + threadIdx.x;
    if (p >= BN) return;
    float tp = pool_time[p];
    ptab[p] = make_float4(tp, expf(0.1f * tp), expf(-0.1f * tp), 0.0f);
}

// query: normalized bf16 row + (tq, e^{+0.1tq}, e^{-0.1tq}, hv)
__global__ __launch_bounds__(64) void qprep_kernel(
    const float* __restrict__ query_emb, const float* __restrict__ query_time,
    const float* __restrict__ inv_qn, const unsigned* __restrict__ minpt,
    u16* __restrict__ qbf, float4* __restrict__ qtab) {
    int q = blockIdx.x, lane = threadIdx.x;
    float iqn = inv_qn[q];
    float4 v = *(const float4*)&query_emb[(size_t)q * HDIM + lane * 4];
    ushort4 o;
    o.x = f2bf(v.x * iqn); o.y = f2bf(v.y * iqn);
    o.z = f2bf(v.z * iqn); o.w = f2bf(v.w * iqn);
    *(ushort4*)&qbf[(size_t)q * HDIM + lane * 4] = o;
    if (lane == 0) {
        float tq = query_time[q];
        float hv = (__uint_as_float(*minpt) < tq) ? 1.0f : 0.0f;
        qtab[q] = make_float4(tq, expf(0.1f * tq), expf(-0.1f * tq), hv);
    }
}

// ================= main: bf16 MFMA sims + candidate top-4 per block =================
__global__ __launch_bounds__(512, 2) void sim_topk_mfma(
    const float* __restrict__ pool_emb,
    const u16* __restrict__ qbf,
    const float4* __restrict__ ptab,
    const float4* __restrict__ qtab,
    const float* __restrict__ inv_pn,
    float4* __restrict__ cand) {
    __shared__ __align__(16) u16 Plds[PB * HDIM];     // 64 KB, 32-slot XOR swizzle
    __shared__ __align__(16) u16 Qlds[2][QI * BK];    // 2 x 32 KB, 8-slot XOR swizzle
    __shared__ __align__(16) float4 ptab_s[PB];       // 2 KB
    __shared__ __align__(16) float4 cand_s[2][QI][2]; // 16 KB

    const int tid = threadIdx.x;
    const int l = tid & 63;
    const int w = tid >> 6;
    const int pw = w >> 2;       // 0..1
    const int qw = w & 3;        // 0..3
    const int l31 = l & 31;
    const int lhi = l >> 5;      // 0..1
    const int p_base = blockIdx.x * PB;

    // ---- prologue: stage this block's 128 pool rows, normalized bf16, swizzled ----
    {
        const int r = tid >> 2;     // 0..127
        const int c = tid & 3;      // quarter of the row (64 elems)
        const float ipn = inv_pn[p_base + r];
        const float* src = &pool_emb[(size_t)(p_base + r) * HDIM + c * 64];
        #pragma unroll
        for (int j2 = 0; j2 < 8; ++j2) {
            float4 x = *(const float4*)&src[j2 * 8];
            float4 y = *(const float4*)&src[j2 * 8 + 4];
            uint4 u;
            u.x = (unsigned)f2bf(x.x * ipn) | ((unsigned)f2bf(x.y * ipn) << 16);
            u.y = (unsigned)f2bf(x.z * ipn) | ((unsigned)f2bf(x.w * ipn) << 16);
            u.z = (unsigned)f2bf(y.x * ipn) | ((unsigned)f2bf(y.y * ipn) << 16);
            u.w = (unsigned)f2bf(y.z * ipn) | ((unsigned)f2bf(y.w * ipn) << 16);
            int s = c * 8 + j2;             // k-group (16B = 8 bf16)
            int sp = s ^ (r & 31);          // swizzled slot
            *(uint4*)&Plds[r * 256 + sp * 8] = u;
        }
        if (tid < PB) ptab_s[tid] = ptab[p_base + tid];
    }

    const float4* qbf4 = (const float4*)qbf;   // row = 32 float4
    const int sr = tid >> 1;    // staging row 0..255
    const int sh = tid & 1;     // staging half

    for (int qi = 0; qi < NQI; ++qi) {
        const int q0 = qi * QI;
        // stage Q chunk 0 into buf 0
        {
            const float4* s0 = &qbf4[(size_t)(q0 + sr) * 32 + sh * 4];
            #pragma unroll
            for (int j = 0; j < 4; ++j) {
                float4 u = s0[j];
                int s = sh * 4 + j;
                int sp = s ^ (sr & 7);
                *(float4*)&Qlds[0][sr * 64 + sp * 8] = u;
            }
        }
        __syncthreads();   // also covers P prologue on qi==0

        f32x16 acc[2][2];
        #pragma unroll
        for (int mt = 0; mt < 2; ++mt)
            #pragma unroll
            for (int nt = 0; nt < 2; ++nt)
                #pragma unroll
                for (int v = 0; v < 16; ++v) acc[mt][nt][v] = 0.0f;

        #pragma unroll
        for (int kc = 0; kc < NKC; ++kc) {
            float4 ld[4];
            if (kc < NKC - 1) {   // prefetch next chunk (raw bf16 copy)
                const float4* sN = &qbf4[(size_t)(q0 + sr) * 32 + (kc + 1) * 8 + sh * 4];
                #pragma unroll
                for (int j = 0; j < 4; ++j) ld[j] = sN[j];
            }
            #pragma unroll
            for (int kt = 0; kt < 4; ++kt) {
                const int gA = (kc * 4 + kt) * 2 + lhi;   // 0..31
                const int gB = kt * 2 + lhi;              // 0..7
                bf16x8 a[2], b[2];
                #pragma unroll
                for (int mt = 0; mt < 2; ++mt) {
                    int row = pw * 64 + mt * 32 + l31;    // row&31 == l31
                    a[mt] = *(const bf16x8*)&Plds[row * 256 + (gA ^ l31) * 8];
                }
                #pragma unroll
                for (int nt = 0; nt < 2; ++nt) {
                    int row = qw * 64 + nt * 32 + l31;    // row&7 == l&7
                    b[nt] = *(const bf16x8*)&Qlds[kc & 1][row * 64 + (gB ^ (l & 7)) * 8];
                }
                #pragma unroll
                for (int mt = 0; mt < 2; ++mt)
                    #pragma unroll
                    for (int nt = 0; nt < 2; ++nt)
                        acc[mt][nt] = __builtin_amdgcn_mfma_f32_32x32x16_bf16(
                            a[mt], b[nt], acc[mt][nt], 0, 0, 0);
            }
            if (kc < NKC - 1) {
                #pragma unroll
                for (int j = 0; j < 4; ++j) {
                    int s = sh * 4 + j;
                    int sp = s ^ (sr & 7);
                    *(float4*)&Qlds[(kc + 1) & 1][sr * 64 + sp * 8] = ld[j];
                }
            }
            __syncthreads();
        }

        // ---- epilogue: decay + mask + per-lane top-4 per q ----
        float Lv[2][4]; int Li[2][4];
        float tqv[2], qepv[2], qemv[2]; bool hvb[2];
        #pragma unroll
        for (int nt = 0; nt < 2; ++nt) {
            int q = q0 + qw * 64 + nt * 32 + l31;
            float4 qt = qtab[q];
            tqv[nt] = qt.x; qepv[nt] = qt.y; qemv[nt] = qt.z; hvb[nt] = qt.w > 0.5f;
            #pragma unroll
            for (int s = 0; s < 4; ++s) { Lv[nt][s] = -INFINITY; Li[nt][s] = 0x7fffffff; }
        }
        #pragma unroll
        for (int nt = 0; nt < 2; ++nt) {
            #pragma unroll
            for (int mt = 0; mt < 2; ++mt) {
                #pragma unroll
                for (int v = 0; v < 16; ++v) {
                    float a = acc[mt][nt][v];
                    float vmax = fmaxf(a, MINDECAY * a);   // upper bound of a*decay
                    if (!(vmax < Lv[nt][3])) {
                        int pl = pw * 64 + mt * 32 + (v & 3) + 8 * (v >> 2) + 4 * lhi;
                        float4 pt = ptab_s[pl];
                        float decay = fminf(qemv[nt] * pt.y, qepv[nt] * pt.z); // = e^{-0.1|dt|}
                        float val = a * decay;
                        if (hvb[nt] && !(pt.x < tqv[nt])) val = -INFINITY;
                        int idx = p_base + pl;
                        if (lexgt(val, idx, Lv[nt][3], Li[nt][3])) {
                            Lv[nt][3] = val; Li[nt][3] = idx;
                            #pragma unroll
                            for (int s = 3; s > 0; --s) {
                                if (lexgt(Lv[nt][s], Li[nt][s], Lv[nt][s - 1], Li[nt][s - 1])) {
                                    float tv = Lv[nt][s]; Lv[nt][s] = Lv[nt][s - 1]; Lv[nt][s - 1] = tv;
                                    int ti = Li[nt][s]; Li[nt][s] = Li[nt][s - 1]; Li[nt][s - 1] = ti;
                                }
                            }
                        }
                    }
                }
            }
            // merge lane pair (l, l^32): both halves of the 32 p-rows
            float ov[4]; int oi[4];
            #pragma unroll
            for (int s = 0; s < 4; ++s) {
                ov[s] = __shfl_xor(Lv[nt][s], 32);
                oi[s] = __shfl_xor(Li[nt][s], 32);
            }
            merge_top4(Lv[nt], Li[nt], ov, oi);
            if (l < 32) {
                int qrow = qw * 64 + nt * 32 + l;
                cand_s[pw][qrow][0] = make_float4(Lv[nt][0], __int_as_float(Li[nt][0]),
                                                  Lv[nt][1], __int_as_float(Li[nt][1]));
                cand_s[pw][qrow][1] = make_float4(Lv[nt][2], __int_as_float(Li[nt][2]),
                                                  Lv[nt][3], __int_as_float(Li[nt][3]));
            }
        }
        __syncthreads();
        // block merge across the two p-waves: one thread per q
        if (tid < QI) {
            float av[4], bv[4]; int ai[4], bi[4];
            float4 x0 = cand_s[0][tid][0], x1 = cand_s[0][tid][1];
            float4 y0 = cand_s[1][tid][0], y1 = cand_s[1][tid][1];
            av[0] = x0.x; ai[0] = __float_as_int(x0.y);
            av[1] = x0.z; ai[1] = __float_as_int(x0.w);
            av[2] = x1.x; ai[2] = __float_as_int(x1.y);
            av[3] = x1.z; ai[3] = __float_as_int(x1.w);
            bv[0] = y0.x; bi[0] = __float_as_int(y0.y);
            bv[1] = y0.z; bi[1] = __float_as_int(y0.w);
            bv[2] = y1.x; bi[2] = __float_as_int(y1.y);
            bv[3] = y1.z; bi[3] = __float_as_int(y1.w);
            merge_top4(av, ai, bv, bi);
            size_t o = ((size_t)(q0 + tid) * NPB + blockIdx.x) * 2;
            cand[o]     = make_float4(av[0], __int_as_float(ai[0]), av[1], __int_as_float(ai[1]));
            cand[o + 1] = make_float4(av[2], __int_as_float(ai[2]), av[3], __int_as_float(ai[3]));
        }
        __syncthreads();
    }
}

// ================= finalize: merge candidates, exact rescore, attention, score =================
__global__ __launch_bounds__(64) void finalize_mfma(
    const float* __restrict__ pool_emb, const float* __restrict__ query_emb,
    const float* __restrict__ pool_time, const float* __restrict__ query_time,
    const float* __restrict__ inv_pn, const float* __restrict__ inv_qn,
    const unsigned* __restrict__ minpt,
    const float4* __restrict__ cand,
    float* __restrict__ out) {
    const int q = blockIdx.x;
    const int lane = threadIdx.x;
    const float tq = query_time[q];
    const bool hv = (__uint_as_float(*minpt) < tq);
    const float iqn = inv_qn[q];

    // per-lane top-16 over this lane's 32 approx candidates
    float Sv[16]; int Si[16];
    #pragma unroll
    for (int s = 0; s < 16; ++s) { Sv[s] = -INFINITY; Si[s] = 0x7fffffff; }
    const float4* base = &cand[(size_t)q * (NPB * 2)];
    #pragma unroll
    for (int j = 0; j < 16; ++j) {
        float4 e = base[j * 64 + lane];
        #pragma unroll
        for (int h = 0; h < 2; ++h) {
            float v = h ? e.z : e.x;
            int ix = __float_as_int(h ? e.w : e.y);
            if (lexgt(v, ix, Sv[15], Si[15])) {
                Sv[15] = v; Si[15] = ix;
                #pragma unroll
                for (int s = 15; s > 0; --s) {
                    if (lexgt(Sv[s], Si[s], Sv[s - 1], Si[s - 1])) {
                        float tv = Sv[s]; Sv[s] = Sv[s - 1]; Sv[s - 1] = tv;
                        int ti = Si[s]; Si[s] = Si[s - 1]; Si[s - 1] = ti;
                    }
                }
            }
        }
    }
    // global approx top-16 via 16 argmax-extract rounds
    int idx16[16];
    #pragma unroll
    for (int k = 0; k < 16; ++k) {
        float cv = Sv[0]; int ci = Si[0];
        #pragma unroll
        for (int off = 1; off < 64; off <<= 1) {
            float ovv = __shfl_xor(cv, off); int ovi = __shfl_xor(ci, off);
            if (lexgt(ovv, ovi, cv, ci)) { cv = ovv; ci = ovi; }
        }
        idx16[k] = ci;
        if (Si[0] == ci) {   // pop my head
            #pragma unroll
            for (int s = 0; s < 15; ++s) { Sv[s] = Sv[s + 1]; Si[s] = Si[s + 1]; }
            Sv[15] = -INFINITY; Si[15] = 0x7fffffff;
        }
    }
    // exact fp32 rescore of the 16 finalists
    const float4 qv = *(const float4*)&query_emb[(size_t)q * HDIM + lane * 4];
    float myv = -INFINITY; int myi = 0x7fffffff;
    #pragma unroll
    for (int k = 0; k < 16; ++k) {
        int ix = idx16[k];
        float vex = -INFINITY;
        if (ix >= 0 && ix < BN) {
            float4 pe = *(const float4*)&pool_emb[(size_t)ix * HDIM + lane * 4];
            float d = qv.x * pe.x + qv.y * pe.y + qv.z * pe.z + qv.w * pe.w;
            #pragma unroll
            for (int off = 32; off >= 1; off >>= 1) d += __shfl_xor(d, off);
            float tp = pool_time[ix];
            float sim = d * (iqn * inv_pn[ix]) * expf(-0.1f * fabsf(tq - tp));
            vex = (hv && !(tp < tq)) ? -INFINITY : sim;
        }
        if (lane == k) { myv = vex; myi = ix; }
    }
    // exact top-7 (lanes 0..15 each own one finalist)
    int ri[TOPK]; int z = 0;
    #pragma unroll
    for (int k = 0; k < TOPK; ++k) {
        float cv = myv; int ci = myi;
        #pragma unroll
        for (int off = 1; off < 64; off <<= 1) {
            float ovv = __shfl_xor(cv, off); int ovi = __shfl_xor(ci, off);
            if (lexgt(ovv, ovi, cv, ci)) { cv = ovv; ci = ovi; }
        }
        if (myi == ci) myv = -INFINITY;  // knockout winner
        if (cv == -INFINITY) { ri[k] = z; z++; }  // ref: -inf slots pick indices 0,1,2,...
        else ri[k] = ci;
    }
    // cross-attention fusion + deviation score (exact, as in R1)
    float4 rk[TOPK]; float lg[TOPK];
    #pragma unroll
    for (int k = 0; k < TOPK; ++k) {
        rk[k] = *(const float4*)&pool_emb[(size_t)ri[k] * HDIM + lane * 4];
        float d = qv.x * rk[k].x + qv.y * rk[k].y + qv.z * rk[k].z + qv.w * rk[k].w;
        #pragma unroll
        for (int off = 32; off >= 1; off >>= 1) d += __shfl_xor(d, off);
        lg[k] = d * 0.0625f;
    }
    float m = lg[0];
    #pragma unroll
    for (int k = 1; k < TOPK; ++k) m = fmaxf(m, lg[k]);
    float e[TOPK], se = 0.0f;
    #pragma unroll
    for (int k = 0; k < TOPK; ++k) { e[k] = expf(lg[k] - m); se += e[k]; }
    float inv_se = 1.0f / se;
    float4 f = make_float4(0.f, 0.f, 0.f, 0.f);
    #pragma unroll
    for (int k = 0; k < TOPK; ++k) {
        float a = e[k] * inv_se;
        f.x += a * rk[k].x; f.y += a * rk[k].y; f.z += a * rk[k].z; f.w += a * rk[k].w;
    }
    float dqf = qv.x * f.x + qv.y * f.y + qv.z * f.z + qv.w * f.w;
    float nq = qv.x * qv.x + qv.y * qv.y + qv.z * qv.z + qv.w * qv.w;
    float nf = f.x * f.x + f.y * f.y + f.z * f.z + f.w * f.w;
    float dx = qv.x - f.x, dy = qv.y - f.y, dz = qv.z - f.z, dw = qv.w - f.w;
    float d2 = dx * dx + dy * dy + dz * dz + dw * dw;
    #pragma unroll
    for (int off = 32; off >= 1; off >>= 1) {
        dqf += __shfl_xor(dqf, off);
        nq += __shfl_xor(nq, off);
        nf += __shfl_xor(nf, off);
        d2 += __shfl_xor(d2, off);
    }
    if (lane == 0) {
        float cosv = dqf / fmaxf(sqrtf(nq) * sqrtf(nf), 1e-8f);
        float l2 = sqrtf(d2);
        out[q] = 0.5f * (1.0f - cosv) + 0.5f * l2;
    }
}

// ================= fallback path (round-1 fp32 kernels) =================
#define PPAD 20
__global__ __launch_bounds__(512, 2) void sim_topk_kernel(
    const float* __restrict__ pool_emb, const float* __restrict__ pool_time,
    const float* __restrict__ query_emb, const float* __restrict__ query_time,
    const float* __restrict__ inv_pn, const float* __restrict__ inv_qn,
    const unsigned* __restrict__ minpt,
    float* __restrict__ pv, int* __restrict__ pi) {
    __shared__ __align__(16) float q_s[QT][HDIM];
    __shared__ __align__(16) float p_s[2][NT][PPAD];
    const int tid = threadIdx.x;
    const int ty = tid >> 6;
    const int tx = tid & 63;
    const int split = blockIdx.x & 7;
    const int qb = blockIdx.x >> 3;
    const int qbase = qb * QT;
    #pragma unroll
    for (int k = 0; k < 4; ++k) {
        int c = tid + k * 512;
        int row = c >> 6;
        int col = (c & 63) << 2;
        *(float4*)&q_s[row][col] = *(const float4*)&query_emb[(size_t)(qbase + row) * HDIM + col];
    }
    float tq[4], qiv[4], qep[4], qem[4];
    bool hv[4];
    float tv[4][TOPK];
    int tix[4][TOPK];
    const float mpt = __uint_as_float(*minpt);
    #pragma unroll
    for (int iq = 0; iq < 4; ++iq) {
        int q = qbase + ty * 4 + iq;
        tq[iq] = query_time[q];
        qiv[iq] = inv_qn[q];
        hv[iq] = (mpt < tq[iq]);
        qep[iq] = expf(0.1f * tq[iq]);
        qem[iq] = expf(-0.1f * tq[iq]);
        #pragma unroll
        for (int s = 0; s < TOPK; ++s) { tv[iq][s] = -INFINITY; tix[iq][s] = 0x7fffffff; }
    }
    auto stage = [&](int b, int pb, int hs) {
        #pragma unroll
        for (int k = 0; k < 2; ++k) {
            int c = tid * 2 + k;
            int row = c >> 2;
            int c4 = c & 3;
            *(float4*)&p_s[b][row][c4 * 4] =
                *(const float4*)&pool_emb[(size_t)(pb + row) * HDIM + hs * 16 + c4 * 4];
        }
    };
    for (int t = 0; t < NTILES; ++t) {
        const int pb = split * (BN / PSPLIT) + t * NT;
        float acc[4][4];
        #pragma unroll
        for (int iq = 0; iq < 4; ++iq)
            #pragma unroll
            for (int jp = 0; jp < 4; ++jp) acc[iq][jp] = 0.0f;
        stage(0, pb, 0);
        __syncthreads();
        for (int hs = 0; hs < 16; ++hs) {
            if (hs < 15) stage((hs + 1) & 1, pb, hs + 1);
            const int b = hs & 1;
            #pragma unroll
            for (int c4 = 0; c4 < 4; ++c4) {
                float4 qf[4];
                #pragma unroll
                for (int iq = 0; iq < 4; ++iq)
                    qf[iq] = *(const float4*)&q_s[ty * 4 + iq][hs * 16 + c4 * 4];
                float4 pf[4];
                #pragma unroll
                for (int jp = 0; jp < 4; ++jp)
                    pf[jp] = *(const float4*)&p_s[b][tx + 64 * jp][c4 * 4];
                #pragma unroll
                for (int iq = 0; iq < 4; ++iq) {
                    #pragma unroll
                    for (int jp = 0; jp < 4; ++jp) {
                        acc[iq][jp] += qf[iq].x * pf[jp].x;
                        acc[iq][jp] += qf[iq].y * pf[jp].y;
                        acc[iq][jp] += qf[iq].z * pf[jp].z;
                        acc[iq][jp] += qf[iq].w * pf[jp].w;
                    }
                }
            }
            __syncthreads();
        }
        #pragma unroll
        for (int jp = 0; jp < 4; ++jp) {
            int pj = pb + tx + 64 * jp;
            float tp = pool_time[pj];
            float piv = inv_pn[pj];
            float ep = expf(0.1f * tp), em = expf(-0.1f * tp);
            #pragma unroll
            for (int iq = 0; iq < 4; ++iq) {
                float decay = fminf(qem[iq] * ep, qep[iq] * em);
                float v = acc[iq][jp] * (qiv[iq] * piv) * decay;
                bool causal = tp < tq[iq];
                if (hv[iq] && !causal) v = -INFINITY;
                if (lexgt(v, pj, tv[iq][TOPK - 1], tix[iq][TOPK - 1])) {
                    tv[iq][TOPK - 1] = v; tix[iq][TOPK - 1] = pj;
                    #pragma unroll
                    for (int s = TOPK - 1; s > 0; --s) {
                        if (lexgt(tv[iq][s], tix[iq][s], tv[iq][s - 1], tix[iq][s - 1])) {
                            float fv = tv[iq][s]; tv[iq][s] = tv[iq][s - 1]; tv[iq][s - 1] = fv;
                            int ii = tix[iq][s]; tix[iq][s] = tix[iq][s - 1]; tix[iq][s - 1] = ii;
                        }
                    }
                }
            }
        }
    }
    #define CE(a, b) { if (lexgt(tv[iq][b], tix[iq][b], tv[iq][a], tix[iq][a])) { \
        float fv = tv[iq][a]; tv[iq][a] = tv[iq][b]; tv[iq][b] = fv;              \
        int ii = tix[iq][a]; tix[iq][a] = tix[iq][b]; tix[iq][b] = ii; } }
    #pragma unroll
    for (int off = 1; off < 64; off <<= 1) {
        #pragma unroll
        for (int iq = 0; iq < 4; ++iq) {
            float ov[TOPK]; int oi[TOPK];
            #pragma unroll
            for (int s = 0; s < TOPK; ++s) {
                ov[s] = __shfl_xor(tv[iq][s], off);
                oi[s] = __shfl_xor(tix[iq][s], off);
            }
            #pragma unroll
            for (int i = 0; i < TOPK; ++i) {
                if (lexgt(ov[6 - i], oi[6 - i], tv[iq][i], tix[iq][i])) {
                    tv[iq][i] = ov[6 - i]; tix[iq][i] = oi[6 - i];
                }
            }
            CE(0, 1); CE(2, 3); CE(4, 5);
            CE(0, 2); CE(1, 3); CE(4, 6);
            CE(1, 2); CE(5, 6);
            CE(0, 4); CE(1, 5); CE(2, 6);
            CE(2, 4); CE(3, 5);
            CE(1, 2); CE(3, 4); CE(5, 6);
        }
    }
    #undef CE
    if (tx == 0) {
        #pragma unroll
        for (int iq = 0; iq < 4; ++iq) {
            int q = qbase + ty * 4 + iq;
            #pragma unroll
            for (int s = 0; s < TOPK; ++s) {
                pv[(q * PSPLIT + split) * TOPK + s] = tv[iq][s];
                pi[(q * PSPLIT + split) * TOPK + s] = tix[iq][s];
            }
        }
    }
}

__global__ __launch_bounds__(64) void finalize_kernel(
    const float* __restrict__ pool_emb, const float* __restrict__ query_emb,
    const float* __restrict__ pv, const int* __restrict__ pi,
    float* __restrict__ out) {
    const int q = blockIdx.x;
    const int lane = threadIdx.x;
    float v = -INFINITY; int ix = 0x7fffffff;
    if (lane < PSPLIT * TOPK) {
        v = pv[q * PSPLIT * TOPK + lane];
        ix = pi[q * PSPLIT * TOPK + lane];
    }
    int ri[TOPK];
    #pragma unroll
    for (int k = 0; k < TOPK; ++k) {
        float mv = v; int mi = ix;
        #pragma unroll
        for (int off = 32; off >= 1; off >>= 1) {
            float v2 = __shfl_xor(mv, off);
            int i2 = __shfl_xor(mi, off);
            if (lexgt(v2, i2, mv, mi)) { mv = v2; mi = i2; }
        }
        ri[k] = mi;
        if (ix == mi) { v = -INFINITY; ix = 0x7fffffff; }
    }
    const float4 qv = *(const float4*)&query_emb[(size_t)q * HDIM + lane * 4];
    float4 rk[TOPK];
    float lg[TOPK];
    #pragma unroll
    for (int k = 0; k < TOPK; ++k) {
        int gi = (ri[k] >= 0 && ri[k] < BN) ? ri[k] : 0;
        rk[k] = *(const float4*)&pool_emb[(size_t)gi * HDIM + lane * 4];
        float d = qv.x * rk[k].x + qv.y * rk[k].y + qv.z * rk[k].z + qv.w * rk[k].w;
        #pragma unroll
        for (int off = 32; off >= 1; off >>= 1) d += __shfl_xor(d, off);
        lg[k] = d * 0.0625f;
    }
    float m = lg[0];
    #pragma unroll
    for (int k = 1; k < TOPK; ++k) m = fmaxf(m, lg[k]);
    float e[TOPK], se = 0.0f;
    #pragma unroll
    for (int k = 0; k < TOPK; ++k) { e[k] = expf(lg[k] - m); se += e[k]; }
    float inv_se = 1.0f / se;
    float4 f = make_float4(0.f, 0.f, 0.f, 0.f);
    #pragma unroll
    for (int k = 0; k < TOPK; ++k) {
        float a = e[k] * inv_se;
        f.x += a * rk[k].x; f.y += a * rk[k].y; f.z += a * rk[k].z; f.w += a * rk[k].w;
    }
    float dqf = qv.x * f.x + qv.y * f.y + qv.z * f.z + qv.w * f.w;
    float nq = qv.x * qv.x + qv.y * qv.y + qv.z * qv.z + qv.w * qv.w;
    float nf = f.x * f.x + f.y * f.y + f.z * f.z + f.w * f.w;
    float dx = qv.x - f.x, dy = qv.y - f.y, dz = qv.z - f.z, dw = qv.w - f.w;
    float d2 = dx * dx + dy * dy + dz * dz + dw * dw;
    #pragma unroll
    for (int off = 32; off >= 1; off >>= 1) {
        dqf += __shfl_xor(dqf, off);
        nq += __shfl_xor(nq, off);
        nf += __shfl_xor(nf, off);
        d2 += __shfl_xor(d2, off);
    }
    if (lane == 0) {
        float cosv = dqf / fmaxf(sqrtf(nq) * sqrtf(nf), 1e-8f);
        float l2 = sqrtf(d2);
        out[q] = 0.5f * (1.0f - cosv) + 0.5f * l2;
    }
}

// ================= launch =================
extern "C" void kernel_launch(void* const* d_in, const int* in_sizes, int n_in,
                              void* d_out, int out_size, void* d_ws, size_t ws_size,
                              hipStream_t stream) {
    (void)in_sizes; (void)n_in; (void)out_size;
    const float* query_emb  = (const float*)d_in[0];
    const float* query_time = (const float*)d_in[1];
    const float* pool_emb   = (const float*)d_in[2];
    const float* pool_time  = (const float*)d_in[3];
    float* out = (float*)d_out;

    char* base = (char*)d_ws;
    size_t off = 0;
    auto take = [&](size_t bytes) -> char* {
        off = (off + 255) & ~(size_t)255;
        char* p = base + off;
        off += bytes;
        return p;
    };

    float* inv_pn  = (float*)take((size_t)BN * 4);
    float* inv_qn  = (float*)take((size_t)BQ * 4);
    unsigned* minpt = (unsigned*)take(16);
    float4* ptab   = (float4*)take((size_t)BN * 16);
    float4* qtab   = (float4*)take((size_t)BQ * 16);
    u16* qbf       = (u16*)take((size_t)BQ * HDIM * 2);
    float4* cand   = (float4*)take((size_t)BQ * NPB * 2 * 16);
    bool newpath = (off <= ws_size);

    if (newpath) {
        hipMemsetAsync(minpt, 0x7F, 4, stream);
        row_norms<<<BN / 4, 256, 0, stream>>>(pool_emb, inv_pn, BN);
        row_norms<<<BQ / 4, 256, 0, stream>>>(query_emb, inv_qn, BQ);
        time_min_kernel<<<64, 256, 0, stream>>>(pool_time, minpt, BN);
        pprep_kernel<<<BN / 256, 256, 0, stream>>>(pool_time, ptab);
        qprep_kernel<<<BQ, 64, 0, stream>>>(query_emb, query_time, inv_qn, minpt, qbf, qtab);
        sim_topk_mfma<<<NPB, 512, 0, stream>>>(pool_emb, qbf, ptab, qtab, inv_pn, cand);
        finalize_mfma<<<BQ, 64, 0, stream>>>(pool_emb, query_emb, pool_time, query_time,
                                             inv_pn, inv_qn, minpt, cand, out);
    } else {
        off = 0;
        float* inv_pn2  = (float*)take((size_t)BN * 4);
        float* inv_qn2  = (float*)take((size_t)BQ * 4);
        unsigned* minpt2 = (unsigned*)take(16);
        float* pv = (float*)take((size_t)BQ * PSPLIT * TOPK * 4);
        int* pi   = (int*)take((size_t)BQ * PSPLIT * TOPK * 4);
        hipMemsetAsync(minpt2, 0x7F, 4, stream);
        row_norms<<<BN / 4, 256, 0, stream>>>(pool_emb, inv_pn2, BN);
        row_norms<<<BQ / 4, 256, 0, stream>>>(query_emb, inv_qn2, BQ);
        time_min_kernel<<<64, 256, 0, stream>>>(pool_time, minpt2, BN);
        sim_topk_kernel<<<(BQ / QT) * PSPLIT, 512, 0, stream>>>(
            pool_emb, pool_time, query_emb, query_time, inv_pn2, inv_qn2, minpt2, pv, pi);
        finalize_kernel<<<BQ, 64, 0, stream>>>(pool_emb, query_emb, pv, pi, out);
    }
}

// Round 5
// 348.374 us; speedup vs baseline: 4.5870x; 2.0048x over previous
//
#include <hip/hip_runtime.h>
#include <math.h>

#define BQ 2048
#define BN 65536
#define HDIM 256
#define TOPK 7

// ---- new-path geometry ----
#define PB 128               // pool rows per block
#define NPB (BN / PB)        // 512 blocks
#define QI 256               // queries per qi-iteration
#define NQI (BQ / QI)        // 8
#define MINDECAY 0.904837f   // exp(-0.1*1)
#define NFIN 12              // finalists rescored exactly

// ---- old-path geometry (fallback) ----
#define PSPLIT 8
#define QT 32
#define NT 256
#define NTILES (BN / PSPLIT / NT)

typedef unsigned short u16;
using bf16x8 = __attribute__((ext_vector_type(8))) short;
using f32x16 = __attribute__((ext_vector_type(16))) float;

__device__ __forceinline__ bool lexgt(float v1, int i1, float v2, int i2) {
    // (v1,i1) strictly ahead of (v2,i2): value desc, index asc
    return (v1 > v2) || (v1 == v2 && i1 < i2);
}

__device__ __forceinline__ u16 f2bf(float f) {
    unsigned u = __float_as_uint(f);
    unsigned r = (u + 0x7fffu + ((u >> 16) & 1u)) >> 16;
    return (u16)r;
}

__device__ __forceinline__ void ce4(float& va, int& ia, float& vb, int& ib) {
    if (lexgt(vb, ib, va, ia)) {
        float t = va; va = vb; vb = t;
        int ti = ia; ia = ib; ib = ti;
    }
}
__device__ __forceinline__ void sort4(float (&V)[4], int (&I)[4]) {
    ce4(V[0], I[0], V[2], I[2]); ce4(V[1], I[1], V[3], I[3]);
    ce4(V[0], I[0], V[1], I[1]); ce4(V[2], I[2], V[3], I[3]);
}
__device__ __forceinline__ void merge_top4(float (&V)[4], int (&I)[4],
                                           const float (&W)[4], const int (&J)[4]) {
    #pragma unroll
    for (int s = 0; s < 4; ++s)
        if (lexgt(W[3 - s], J[3 - s], V[s], I[s])) { V[s] = W[3 - s]; I[s] = J[3 - s]; }
    sort4(V, I);
}

// ================= prep kernels =================
__global__ void row_norms(const float* __restrict__ x, float* __restrict__ inv, int rows) {
    int wid = threadIdx.x >> 6, lane = threadIdx.x & 63;
    int row = blockIdx.x * 4 + wid;
    if (row >= rows) return;
    float4 v = *(const float4*)&x[(size_t)row * HDIM + lane * 4];
    float s = v.x * v.x + v.y * v.y + v.z * v.z + v.w * v.w;
    #pragma unroll
    for (int off = 32; off >= 1; off >>= 1) s += __shfl_xor(s, off);
    if (lane == 0) inv[row] = 1.0f / fmaxf(sqrtf(s), 1e-12f);
}

__global__ void time_min_kernel(const float* __restrict__ t, unsigned* __restrict__ m, int n) {
    float mn = 3.0e38f;
    for (int i = blockIdx.x * blockDim.x + threadIdx.x; i < n; i += gridDim.x * blockDim.x)
        mn = fminf(mn, t[i]);
    #pragma unroll
    for (int off = 32; off >= 1; off >>= 1) mn = fminf(mn, __shfl_xor(mn, off));
    __shared__ float wmin[4];
    int wid = threadIdx.x >> 6, lane = threadIdx.x & 63;
    if (lane == 0) wmin[wid] = mn;
    __syncthreads();
    if (threadIdx.x == 0) {
        float b = fminf(fminf(wmin[0], wmin[1]), fminf(wmin[2], wmin[3]));
        atomicMin(m, __float_as_uint(b));
    }
}

// pool time table: (tp, e^{+0.1tp}, e^{-0.1tp}, 0)
__global__ void pprep_kernel(const float* __restrict__ pool_time, float4* __restrict__ ptab) {
    int p = blockIdx.x * blockDim.x + threadIdx.x;
    if (p >= BN) return;
    float tp = pool_time[p];
    ptab[p] = make_float4(tp, expf(0.1f * tp), expf(-0.1f * tp), 0.0f);
}

// query fragment prep: normalized bf16 in MFMA B-fragment order.
// qfrag layout (u16 units): slab(=q>>5)*8192 + kt*512 + lane*8, where
// lane = ((kg&1)<<5) | (q&31), kt = kg>>1, kg = dim-group of 8.
__global__ __launch_bounds__(256) void qprep2_kernel(
    const float* __restrict__ query_emb, const float* __restrict__ inv_qn,
    u16* __restrict__ qfrag) {
    int gid = blockIdx.x * 256 + threadIdx.x;
    int q = gid >> 5, kg = gid & 31;
    float iqn = inv_qn[q];
    const float* src = &query_emb[(size_t)q * HDIM + kg * 8];
    float4 x = *(const float4*)&src[0];
    float4 y = *(const float4*)&src[4];
    uint4 u;
    u.x = (unsigned)f2bf(x.x * iqn) | ((unsigned)f2bf(x.y * iqn) << 16);
    u.y = (unsigned)f2bf(x.z * iqn) | ((unsigned)f2bf(x.w * iqn) << 16);
    u.z = (unsigned)f2bf(y.x * iqn) | ((unsigned)f2bf(y.y * iqn) << 16);
    u.w = (unsigned)f2bf(y.z * iqn) | ((unsigned)f2bf(y.w * iqn) << 16);
    unsigned idx = (unsigned)(q >> 5) * 8192u + (unsigned)(kg >> 1) * 512u
                 + ((unsigned)((kg & 1) << 5) + (unsigned)(q & 31)) * 8u;
    *(uint4*)&qfrag[idx] = u;
}

// query time table: (tq, e^{+0.1tq}, e^{-0.1tq}, hv)
__global__ __launch_bounds__(256) void qtab_kernel(
    const float* __restrict__ query_time, const unsigned* __restrict__ minpt,
    float4* __restrict__ qtab) {
    int q = blockIdx.x * 256 + threadIdx.x;
    if (q >= BQ) return;
    float tq = query_time[q];
    float hv = (__uint_as_float(*minpt) < tq) ? 1.0f : 0.0f;
    qtab[q] = make_float4(tq, expf(0.1f * tq), expf(-0.1f * tq), hv);
}

// ================= main: bf16 MFMA sims + candidate top-4 per block =================
// 8 waves: pw = w>>2 (2 p-halves of 64 rows), qw = w&3 (4 q-quarters of 64).
// P in LDS, fragment order; Q streamed from global fragment order (L2).
// K-loop has NO barriers.
__global__ __launch_bounds__(512, 4) void sim_topk_mfma2(
    const float* __restrict__ pool_emb,
    const u16* __restrict__ qfrag,
    const float4* __restrict__ ptab,
    const float4* __restrict__ qtab,
    const float* __restrict__ inv_pn,
    float4* __restrict__ cand) {
    __shared__ __align__(16) u16 Plds[PB * HDIM];     // 64 KB, A-fragment layout
    __shared__ __align__(16) float4 ptab_s[PB];       // 2 KB
    __shared__ __align__(16) float4 cand_s[QI][2];    // 8 KB

    const int tid = threadIdx.x;
    const int l = tid & 63;
    const int w = tid >> 6;
    const int pw = w >> 2;       // 0..1
    const int qw = w & 3;        // 0..3
    const int l31 = l & 31;
    const int lhi = l >> 5;      // 0..1
    const int p_base = blockIdx.x * PB;

    // ---- prologue: stage 128 pool rows, normalized bf16, A-fragment layout ----
    {
        const int r = tid >> 2;     // 0..127
        const int c = tid & 3;      // quarter of the row
        const float ipn = inv_pn[p_base + r];
        const float* src = &pool_emb[(size_t)(p_base + r) * HDIM + c * 64];
        const int slab = r >> 5;
        #pragma unroll
        for (int j2 = 0; j2 < 8; ++j2) {
            float4 x = *(const float4*)&src[j2 * 8];
            float4 y = *(const float4*)&src[j2 * 8 + 4];
            uint4 u;
            u.x = (unsigned)f2bf(x.x * ipn) | ((unsigned)f2bf(x.y * ipn) << 16);
            u.y = (unsigned)f2bf(x.z * ipn) | ((unsigned)f2bf(x.w * ipn) << 16);
            u.z = (unsigned)f2bf(y.x * ipn) | ((unsigned)f2bf(y.y * ipn) << 16);
            u.w = (unsigned)f2bf(y.z * ipn) | ((unsigned)f2bf(y.w * ipn) << 16);
            int kg = c * 8 + j2;
            int kt = kg >> 1;
            int lane = ((kg & 1) << 5) | (r & 31);
            *(uint4*)&Plds[slab * 8192 + kt * 512 + lane * 8] = u;
        }
        if (tid < PB) ptab_s[tid] = ptab[p_base + tid];
    }
    __syncthreads();

    // per-wave constant LDS base: a[mt] at Pbase + mt*8192 + kt*512 (u16 units)
    const u16* Pbase = &Plds[pw * 16384 + l * 8];

    for (int qi = 0; qi < NQI; ++qi) {
        const int q0 = qi * QI;
        const int slabB = (qi * 4 + qw) * 2;
        const u16* qb0 = &qfrag[(size_t)slabB * 8192 + l * 8];
        const u16* qb1 = &qfrag[(size_t)(slabB + 1) * 8192 + l * 8];

        f32x16 acc[2][2];
        #pragma unroll
        for (int mt = 0; mt < 2; ++mt)
            #pragma unroll
            for (int nt = 0; nt < 2; ++nt)
                #pragma unroll
                for (int v = 0; v < 16; ++v) acc[mt][nt][v] = 0.0f;

        // ---- K-loop: no barriers; reg-double-buffered A (LDS) and B (global/L2)
        bf16x8 b0c = *(const bf16x8*)qb0;
        bf16x8 b1c = *(const bf16x8*)qb1;
        bf16x8 a0c = *(const bf16x8*)(Pbase);
        bf16x8 a1c = *(const bf16x8*)(Pbase + 8192);
        #pragma unroll
        for (int kt = 0; kt < 16; ++kt) {
            bf16x8 b0n = b0c, b1n = b1c, a0n = a0c, a1n = a1c;
            if (kt < 15) {
                b0n = *(const bf16x8*)(qb0 + (kt + 1) * 512);
                b1n = *(const bf16x8*)(qb1 + (kt + 1) * 512);
                a0n = *(const bf16x8*)(Pbase + (kt + 1) * 512);
                a1n = *(const bf16x8*)(Pbase + 8192 + (kt + 1) * 512);
            }
            acc[0][0] = __builtin_amdgcn_mfma_f32_32x32x16_bf16(a0c, b0c, acc[0][0], 0, 0, 0);
            acc[0][1] = __builtin_amdgcn_mfma_f32_32x32x16_bf16(a0c, b1c, acc[0][1], 0, 0, 0);
            acc[1][0] = __builtin_amdgcn_mfma_f32_32x32x16_bf16(a1c, b0c, acc[1][0], 0, 0, 0);
            acc[1][1] = __builtin_amdgcn_mfma_f32_32x32x16_bf16(a1c, b1c, acc[1][1], 0, 0, 0);
            b0c = b0n; b1c = b1n; a0c = a0n; a1c = a1n;
        }

        // ---- epilogue: decay + mask + per-lane top-4 per q ----
        float Lv[2][4]; int Li[2][4];
        float tqv[2], qepv[2], qemv[2]; bool hvb[2];
        #pragma unroll
        for (int nt = 0; nt < 2; ++nt) {
            int qq = q0 + qw * 64 + nt * 32 + l31;
            float4 qt = qtab[qq];
            tqv[nt] = qt.x; qepv[nt] = qt.y; qemv[nt] = qt.z; hvb[nt] = qt.w > 0.5f;
            #pragma unroll
            for (int s = 0; s < 4; ++s) { Lv[nt][s] = -INFINITY; Li[nt][s] = 0x7fffffff; }
        }
        #pragma unroll
        for (int nt = 0; nt < 2; ++nt) {
            #pragma unroll
            for (int mt = 0; mt < 2; ++mt) {
                #pragma unroll
                for (int v = 0; v < 16; ++v) {
                    float a = acc[mt][nt][v];
                    float vmax = fmaxf(a, MINDECAY * a);   // upper bound of a*decay
                    if (!(vmax < Lv[nt][3])) {
                        int pl = pw * 64 + mt * 32 + (v & 3) + 8 * (v >> 2) + 4 * lhi;
                        float4 pt = ptab_s[pl];
                        float decay = fminf(qemv[nt] * pt.y, qepv[nt] * pt.z); // e^{-0.1|dt|}
                        float val = a * decay;
                        if (hvb[nt] && !(pt.x < tqv[nt])) val = -INFINITY;
                        int idx = p_base + pl;
                        if (lexgt(val, idx, Lv[nt][3], Li[nt][3])) {
                            Lv[nt][3] = val; Li[nt][3] = idx;
                            #pragma unroll
                            for (int s = 3; s > 0; --s) {
                                if (lexgt(Lv[nt][s], Li[nt][s], Lv[nt][s - 1], Li[nt][s - 1])) {
                                    float tv = Lv[nt][s]; Lv[nt][s] = Lv[nt][s - 1]; Lv[nt][s - 1] = tv;
                                    int ti = Li[nt][s]; Li[nt][s] = Li[nt][s - 1]; Li[nt][s - 1] = ti;
                                }
                            }
                        }
                    }
                }
            }
            // merge lane pair (l, l^32): both interleaved halves of this wave's 64 p-rows
            float ov[4]; int oi[4];
            #pragma unroll
            for (int s = 0; s < 4; ++s) {
                ov[s] = __shfl_xor(Lv[nt][s], 32);
                oi[s] = __shfl_xor(Li[nt][s], 32);
            }
            merge_top4(Lv[nt], Li[nt], ov, oi);
        }
        if (pw == 0 && l < 32) {
            #pragma unroll
            for (int nt = 0; nt < 2; ++nt) {
                int qrow = qw * 64 + nt * 32 + l;
                cand_s[qrow][0] = make_float4(Lv[nt][0], __int_as_float(Li[nt][0]),
                                              Lv[nt][1], __int_as_float(Li[nt][1]));
                cand_s[qrow][1] = make_float4(Lv[nt][2], __int_as_float(Li[nt][2]),
                                              Lv[nt][3], __int_as_float(Li[nt][3]));
            }
        }
        __syncthreads();
        if (pw == 1 && l < 32) {
            #pragma unroll
            for (int nt = 0; nt < 2; ++nt) {
                int qrow = qw * 64 + nt * 32 + l;
                float bv[4]; int bi[4];
                float4 y0 = cand_s[qrow][0], y1 = cand_s[qrow][1];
                bv[0] = y0.x; bi[0] = __float_as_int(y0.y);
                bv[1] = y0.z; bi[1] = __float_as_int(y0.w);
                bv[2] = y1.x; bi[2] = __float_as_int(y1.y);
                bv[3] = y1.z; bi[3] = __float_as_int(y1.w);
                merge_top4(Lv[nt], Li[nt], bv, bi);
                size_t o = ((size_t)(q0 + qrow) * NPB + blockIdx.x) * 2;
                cand[o]     = make_float4(Lv[nt][0], __int_as_float(Li[nt][0]),
                                          Lv[nt][1], __int_as_float(Li[nt][1]));
                cand[o + 1] = make_float4(Lv[nt][2], __int_as_float(Li[nt][2]),
                                          Lv[nt][3], __int_as_float(Li[nt][3]));
            }
        }
        __syncthreads();
    }
}

// ================= finalize v2: 256 threads, parallel merge + exact rescore =================
__global__ __launch_bounds__(256) void finalize2(
    const float* __restrict__ pool_emb, const float* __restrict__ query_emb,
    const float* __restrict__ pool_time, const float* __restrict__ query_time,
    const float* __restrict__ inv_pn, const float* __restrict__ inv_qn,
    const unsigned* __restrict__ minpt,
    const float4* __restrict__ cand,
    float* __restrict__ out) {
    __shared__ float2 wred[NFIN][4];
    __shared__ float exv2[NFIN];
    __shared__ int   exi[NFIN];
    __shared__ float ared[4][TOPK + 1];
    __shared__ float sred[4][4];

    const int q = blockIdx.x;
    const int tid = threadIdx.x;
    const int w = tid >> 6, lane = tid & 63;
    const float tq = query_time[q];
    const bool hv = (__uint_as_float(*minpt) < tq);
    const float iqn = inv_qn[q];

    // phase 1: load 8 approx candidates per thread (coalesced)
    float Sv[8]; int Si[8];
    const float4* base = &cand[(size_t)q * (NPB * 2)];
    #pragma unroll
    for (int j = 0; j < 4; ++j) {
        float4 e = base[j * 256 + tid];
        Sv[2 * j]     = e.x; Si[2 * j]     = __float_as_int(e.y);
        Sv[2 * j + 1] = e.z; Si[2 * j + 1] = __float_as_int(e.w);
    }

    // phase 2: NFIN global argmax-extraction rounds (approx order)
    #pragma unroll 1
    for (int r = 0; r < NFIN; ++r) {
        float bv = Sv[0]; int bi = Si[0];
        #pragma unroll
        for (int s = 1; s < 8; ++s)
            if (lexgt(Sv[s], Si[s], bv, bi)) { bv = Sv[s]; bi = Si[s]; }
        #pragma unroll
        for (int off = 32; off >= 1; off >>= 1) {
            float ov = __shfl_xor(bv, off); int oi = __shfl_xor(bi, off);
            if (lexgt(ov, oi, bv, bi)) { bv = ov; bi = oi; }
        }
        if (lane == 0) wred[r][w] = make_float2(bv, __int_as_float(bi));
        __syncthreads();
        float cv = -INFINITY; int ci = 0x7fffffff;
        #pragma unroll
        for (int ww = 0; ww < 4; ++ww) {
            float2 e = wred[r][ww];
            int ei = __float_as_int(e.y);
            if (lexgt(e.x, ei, cv, ci)) { cv = e.x; ci = ei; }
        }
        if (tid == 0) exi[r] = ci;
        #pragma unroll
        for (int s = 0; s < 8; ++s)
            if (Si[s] == ci) { Sv[s] = -INFINITY; Si[s] = 0x7fffffff; }
    }
    __syncthreads();

    // phase 3: exact fp32 rescore of NFIN finalists (wave w does k = w, w+4, w+8)
    const float4 qv4 = *(const float4*)&query_emb[(size_t)q * HDIM + lane * 4];
    #pragma unroll
    for (int j = 0; j < NFIN / 4; ++j) {
        int k = w + 4 * j;
        int ix = exi[k];
        float vex = -INFINITY;
        if (ix >= 0 && ix < BN) {
            float4 pe = *(const float4*)&pool_emb[(size_t)ix * HDIM + lane * 4];
            float d = qv4.x * pe.x + qv4.y * pe.y + qv4.z * pe.z + qv4.w * pe.w;
            #pragma unroll
            for (int off = 32; off >= 1; off >>= 1) d += __shfl_xor(d, off);
            float tp = pool_time[ix];
            float sim = d * (iqn * inv_pn[ix]) * expf(-0.1f * fabsf(tq - tp));
            vex = (hv && !(tp < tq)) ? -INFINITY : sim;
        }
        if (lane == 0) exv2[k] = vex;
    }
    __syncthreads();

    // phase 4: exact top-7 of NFIN (computed redundantly/uniformly by all threads)
    float E[NFIN]; int EI[NFIN];
    #pragma unroll
    for (int s = 0; s < NFIN; ++s) { E[s] = exv2[s]; EI[s] = exi[s]; }
    int ri[TOPK]; int z = 0;
    #pragma unroll
    for (int k2 = 0; k2 < TOPK; ++k2) {
        float bv = E[0]; int bi = EI[0]; int bs = 0;
        #pragma unroll
        for (int s = 1; s < NFIN; ++s)
            if (lexgt(E[s], EI[s], bv, bi)) { bv = E[s]; bi = EI[s]; bs = s; }
        #pragma unroll
        for (int s = 0; s < NFIN; ++s)
            if (s == bs) E[s] = -INFINITY;
        if (bv == -INFINITY) { ri[k2] = z; z++; }  // ref -inf fallback: indices 0,1,2,...
        else ri[k2] = bi;
    }

    // phase 5: cross-attention fusion + deviation score; thread t = dim t
    const float qd = query_emb[(size_t)q * HDIM + tid];
    float rkd[TOPK], part[TOPK];
    #pragma unroll
    for (int k2 = 0; k2 < TOPK; ++k2) {
        rkd[k2] = pool_emb[(size_t)ri[k2] * HDIM + tid];
        part[k2] = qd * rkd[k2];
    }
    #pragma unroll
    for (int k2 = 0; k2 < TOPK; ++k2) {
        float x = part[k2];
        #pragma unroll
        for (int off = 32; off >= 1; off >>= 1) x += __shfl_xor(x, off);
        part[k2] = x;
    }
    if (lane == 0) {
        #pragma unroll
        for (int k2 = 0; k2 < TOPK; ++k2) ared[w][k2] = part[k2];
    }
    __syncthreads();
    float lg[TOPK];
    #pragma unroll
    for (int k2 = 0; k2 < TOPK; ++k2)
        lg[k2] = (ared[0][k2] + ared[1][k2] + ared[2][k2] + ared[3][k2]) * 0.0625f;
    float m = lg[0];
    #pragma unroll
    for (int k2 = 1; k2 < TOPK; ++k2) m = fmaxf(m, lg[k2]);
    float ee[TOPK], se = 0.0f;
    #pragma unroll
    for (int k2 = 0; k2 < TOPK; ++k2) { ee[k2] = expf(lg[k2] - m); se += ee[k2]; }
    float inv_se = 1.0f / se;
    float f = 0.0f;
    #pragma unroll
    for (int k2 = 0; k2 < TOPK; ++k2) f += ee[k2] * inv_se * rkd[k2];
    float p0 = qd * f, p1 = qd * qd, p2 = f * f;
    float dd = qd - f, p3 = dd * dd;
    #pragma unroll
    for (int off = 32; off >= 1; off >>= 1) {
        p0 += __shfl_xor(p0, off);
        p1 += __shfl_xor(p1, off);
        p2 += __shfl_xor(p2, off);
        p3 += __shfl_xor(p3, off);
    }
    if (lane == 0) { sred[w][0] = p0; sred[w][1] = p1; sred[w][2] = p2; sred[w][3] = p3; }
    __syncthreads();
    if (tid == 0) {
        float dqf = sred[0][0] + sred[1][0] + sred[2][0] + sred[3][0];
        float nq  = sred[0][1] + sred[1][1] + sred[2][1] + sred[3][1];
        float nf  = sred[0][2] + sred[1][2] + sred[2][2] + sred[3][2];
        float d2  = sred[0][3] + sred[1][3] + sred[2][3] + sred[3][3];
        float cosv = dqf / fmaxf(sqrtf(nq) * sqrtf(nf), 1e-8f);
        out[q] = 0.5f * (1.0f - cosv) + 0.5f * sqrtf(d2);
    }
}

// ================= fallback path (round-1 fp32 kernels) =================
#define PPAD 20
__global__ __launch_bounds__(512, 2) void sim_topk_kernel(
    const float* __restrict__ pool_emb, const float* __restrict__ pool_time,
    const float* __restrict__ query_emb, const float* __restrict__ query_time,
    const float* __restrict__ inv_pn, const float* __restrict__ inv_qn,
    const unsigned* __restrict__ minpt,
    float* __restrict__ pv, int* __restrict__ pi) {
    __shared__ __align__(16) float q_s[QT][HDIM];
    __shared__ __align__(16) float p_s[2][NT][PPAD];
    const int tid = threadIdx.x;
    const int ty = tid >> 6;
    const int tx = tid & 63;
    const int split = blockIdx.x & 7;
    const int qb = blockIdx.x >> 3;
    const int qbase = qb * QT;
    #pragma unroll
    for (int k = 0; k < 4; ++k) {
        int c = tid + k * 512;
        int row = c >> 6;
        int col = (c & 63) << 2;
        *(float4*)&q_s[row][col] = *(const float4*)&query_emb[(size_t)(qbase + row) * HDIM + col];
    }
    float tq[4], qiv[4], qep[4], qem[4];
    bool hv[4];
    float tv[4][TOPK];
    int tix[4][TOPK];
    const float mpt = __uint_as_float(*minpt);
    #pragma unroll
    for (int iq = 0; iq < 4; ++iq) {
        int q = qbase + ty * 4 + iq;
        tq[iq] = query_time[q];
        qiv[iq] = inv_qn[q];
        hv[iq] = (mpt < tq[iq]);
        qep[iq] = expf(0.1f * tq[iq]);
        qem[iq] = expf(-0.1f * tq[iq]);
        #pragma unroll
        for (int s = 0; s < TOPK; ++s) { tv[iq][s] = -INFINITY; tix[iq][s] = 0x7fffffff; }
    }
    auto stage = [&](int b, int pb, int hs) {
        #pragma unroll
        for (int k = 0; k < 2; ++k) {
            int c = tid * 2 + k;
            int row = c >> 2;
            int c4 = c & 3;
            *(float4*)&p_s[b][row][c4 * 4] =
                *(const float4*)&pool_emb[(size_t)(pb + row) * HDIM + hs * 16 + c4 * 4];
        }
    };
    for (int t = 0; t < NTILES; ++t) {
        const int pb = split * (BN / PSPLIT) + t * NT;
        float acc[4][4];
        #pragma unroll
        for (int iq = 0; iq < 4; ++iq)
            #pragma unroll
            for (int jp = 0; jp < 4; ++jp) acc[iq][jp] = 0.0f;
        stage(0, pb, 0);
        __syncthreads();
        for (int hs = 0; hs < 16; ++hs) {
            if (hs < 15) stage((hs + 1) & 1, pb, hs + 1);
            const int b = hs & 1;
            #pragma unroll
            for (int c4 = 0; c4 < 4; ++c4) {
                float4 qf[4];
                #pragma unroll
                for (int iq = 0; iq < 4; ++iq)
                    qf[iq] = *(const float4*)&q_s[ty * 4 + iq][hs * 16 + c4 * 4];
                float4 pf[4];
                #pragma unroll
                for (int jp = 0; jp < 4; ++jp)
                    pf[jp] = *(const float4*)&p_s[b][tx + 64 * jp][c4 * 4];
                #pragma unroll
                for (int iq = 0; iq < 4; ++iq) {
                    #pragma unroll
                    for (int jp = 0; jp < 4; ++jp) {
                        acc[iq][jp] += qf[iq].x * pf[jp].x;
                        acc[iq][jp] += qf[iq].y * pf[jp].y;
                        acc[iq][jp] += qf[iq].z * pf[jp].z;
                        acc[iq][jp] += qf[iq].w * pf[jp].w;
                    }
                }
            }
            __syncthreads();
        }
        #pragma unroll
        for (int jp = 0; jp < 4; ++jp) {
            int pj = pb + tx + 64 * jp;
            float tp = pool_time[pj];
            float piv = inv_pn[pj];
            float ep = expf(0.1f * tp), em = expf(-0.1f * tp);
            #pragma unroll
            for (int iq = 0; iq < 4; ++iq) {
                float decay = fminf(qem[iq] * ep, qep[iq] * em);
                float v = acc[iq][jp] * (qiv[iq] * piv) * decay;
                bool causal = tp < tq[iq];
                if (hv[iq] && !causal) v = -INFINITY;
                if (lexgt(v, pj, tv[iq][TOPK - 1], tix[iq][TOPK - 1])) {
                    tv[iq][TOPK - 1] = v; tix[iq][TOPK - 1] = pj;
                    #pragma unroll
                    for (int s = TOPK - 1; s > 0; --s) {
                        if (lexgt(tv[iq][s], tix[iq][s], tv[iq][s - 1], tix[iq][s - 1])) {
                            float fv = tv[iq][s]; tv[iq][s] = tv[iq][s - 1]; tv[iq][s - 1] = fv;
                            int ii = tix[iq][s]; tix[iq][s] = tix[iq][s - 1]; tix[iq][s - 1] = ii;
                        }
                    }
                }
            }
        }
    }
    #define CE(a, b) { if (lexgt(tv[iq][b], tix[iq][b], tv[iq][a], tix[iq][a])) { \
        float fv = tv[iq][a]; tv[iq][a] = tv[iq][b]; tv[iq][b] = fv;              \
        int ii = tix[iq][a]; tix[iq][a] = tix[iq][b]; tix[iq][b] = ii; } }
    #pragma unroll
    for (int off = 1; off < 64; off <<= 1) {
        #pragma unroll
        for (int iq = 0; iq < 4; ++iq) {
            float ov[TOPK]; int oi[TOPK];
            #pragma unroll
            for (int s = 0; s < TOPK; ++s) {
                ov[s] = __shfl_xor(tv[iq][s], off);
                oi[s] = __shfl_xor(tix[iq][s], off);
            }
            #pragma unroll
            for (int i = 0; i < TOPK; ++i) {
                if (lexgt(ov[6 - i], oi[6 - i], tv[iq][i], tix[iq][i])) {
                    tv[iq][i] = ov[6 - i]; tix[iq][i] = oi[6 - i];
                }
            }
            CE(0, 1); CE(2, 3); CE(4, 5);
            CE(0, 2); CE(1, 3); CE(4, 6);
            CE(1, 2); CE(5, 6);
            CE(0, 4); CE(1, 5); CE(2, 6);
            CE(2, 4); CE(3, 5);
            CE(1, 2); CE(3, 4); CE(5, 6);
        }
    }
    #undef CE
    if (tx == 0) {
        #pragma unroll
        for (int iq = 0; iq < 4; ++iq) {
            int q = qbase + ty * 4 + iq;
            #pragma unroll
            for (int s = 0; s < TOPK; ++s) {
                pv[(q * PSPLIT + split) * TOPK + s] = tv[iq][s];
                pi[(q * PSPLIT + split) * TOPK + s] = tix[iq][s];
            }
        }
    }
}

__global__ __launch_bounds__(64) void finalize_kernel(
    const float* __restrict__ pool_emb, const float* __restrict__ query_emb,
    const float* __restrict__ pv, const int* __restrict__ pi,
    float* __restrict__ out) {
    const int q = blockIdx.x;
    const int lane = threadIdx.x;
    float v = -INFINITY; int ix = 0x7fffffff;
    if (lane < PSPLIT * TOPK) {
        v = pv[q * PSPLIT * TOPK + lane];
        ix = pi[q * PSPLIT * TOPK + lane];
    }
    int ri[TOPK];
    #pragma unroll
    for (int k = 0; k < TOPK; ++k) {
        float mv = v; int mi = ix;
        #pragma unroll
        for (int off = 32; off >= 1; off >>= 1) {
            float v2 = __shfl_xor(mv, off);
            int i2 = __shfl_xor(mi, off);
            if (lexgt(v2, i2, mv, mi)) { mv = v2; mi = i2; }
        }
        ri[k] = mi;
        if (ix == mi) { v = -INFINITY; ix = 0x7fffffff; }
    }
    const float4 qv = *(const float4*)&query_emb[(size_t)q * HDIM + lane * 4];
    float4 rk[TOPK];
    float lg[TOPK];
    #pragma unroll
    for (int k = 0; k < TOPK; ++k) {
        int gi = (ri[k] >= 0 && ri[k] < BN) ? ri[k] : 0;
        rk[k] = *(const float4*)&pool_emb[(size_t)gi * HDIM + lane * 4];
        float d = qv.x * rk[k].x + qv.y * rk[k].y + qv.z * rk[k].z + qv.w * rk[k].w;
        #pragma unroll
        for (int off = 32; off >= 1; off >>= 1) d += __shfl_xor(d, off);
        lg[k] = d * 0.0625f;
    }
    float m = lg[0];
    #pragma unroll
    for (int k = 1; k < TOPK; ++k) m = fmaxf(m, lg[k]);
    float e[TOPK], se = 0.0f;
    #pragma unroll
    for (int k = 0; k < TOPK; ++k) { e[k] = expf(lg[k] - m); se += e[k]; }
    float inv_se = 1.0f / se;
    float4 f = make_float4(0.f, 0.f, 0.f, 0.f);
    #pragma unroll
    for (int k = 0; k < TOPK; ++k) {
        float a = e[k] * inv_se;
        f.x += a * rk[k].x; f.y += a * rk[k].y; f.z += a * rk[k].z; f.w += a * rk[k].w;
    }
    float dqf = qv.x * f.x + qv.y * f.y + qv.z * f.z + qv.w * f.w;
    float nq = qv.x * qv.x + qv.y * qv.y + qv.z * qv.z + qv.w * qv.w;
    float nf = f.x * f.x + f.y * f.y + f.z * f.z + f.w * f.w;
    float dx = qv.x - f.x, dy = qv.y - f.y, dz = qv.z - f.z, dw = qv.w - f.w;
    float d2 = dx * dx + dy * dy + dz * dz + dw * dw;
    #pragma unroll
    for (int off = 32; off >= 1; off >>= 1) {
        dqf += __shfl_xor(dqf, off);
        nq += __shfl_xor(nq, off);
        nf += __shfl_xor(nf, off);
        d2 += __shfl_xor(d2, off);
    }
    if (lane == 0) {
        float cosv = dqf / fmaxf(sqrtf(nq) * sqrtf(nf), 1e-8f);
        float l2 = sqrtf(d2);
        out[q] = 0.5f * (1.0f - cosv) + 0.5f * l2;
    }
}

// ================= launch =================
extern "C" void kernel_launch(void* const* d_in, const int* in_sizes, int n_in,
                              void* d_out, int out_size, void* d_ws, size_t ws_size,
                              hipStream_t stream) {
    (void)in_sizes; (void)n_in; (void)out_size;
    const float* query_emb  = (const float*)d_in[0];
    const float* query_time = (const float*)d_in[1];
    const float* pool_emb   = (const float*)d_in[2];
    const float* pool_time  = (const float*)d_in[3];
    float* out = (float*)d_out;

    char* base = (char*)d_ws;
    size_t off = 0;
    auto take = [&](size_t bytes) -> char* {
        off = (off + 255) & ~(size_t)255;
        char* p = base + off;
        off += bytes;
        return p;
    };

    float* inv_pn   = (float*)take((size_t)BN * 4);
    float* inv_qn   = (float*)take((size_t)BQ * 4);
    unsigned* minpt = (unsigned*)take(16);
    float4* ptab    = (float4*)take((size_t)BN * 16);
    float4* qtab    = (float4*)take((size_t)BQ * 16);
    u16* qfrag      = (u16*)take((size_t)BQ * HDIM * 2);
    float4* cand    = (float4*)take((size_t)BQ * NPB * 2 * 16);
    bool newpath = (off <= ws_size);

    if (newpath) {
        hipMemsetAsync(minpt, 0x7F, 4, stream);
        row_norms<<<BN / 4, 256, 0, stream>>>(pool_emb, inv_pn, BN);
        row_norms<<<BQ / 4, 256, 0, stream>>>(query_emb, inv_qn, BQ);
        time_min_kernel<<<64, 256, 0, stream>>>(pool_time, minpt, BN);
        pprep_kernel<<<BN / 256, 256, 0, stream>>>(pool_time, ptab);
        qprep2_kernel<<<(BQ * 32) / 256, 256, 0, stream>>>(query_emb, inv_qn, qfrag);
        qtab_kernel<<<BQ / 256, 256, 0, stream>>>(query_time, minpt, qtab);
        sim_topk_mfma2<<<NPB, 512, 0, stream>>>(pool_emb, qfrag, ptab, qtab, inv_pn, cand);
        finalize2<<<BQ, 256, 0, stream>>>(pool_emb, query_emb, pool_time, query_time,
                                          inv_pn, inv_qn, minpt, cand, out);
    } else {
        off = 0;
        float* inv_pn2   = (float*)take((size_t)BN * 4);
        float* inv_qn2   = (float*)take((size_t)BQ * 4);
        unsigned* minpt2 = (unsigned*)take(16);
        float* pv = (float*)take((size_t)BQ * PSPLIT * TOPK * 4);
        int* pi   = (int*)take((size_t)BQ * PSPLIT * TOPK * 4);
        hipMemsetAsync(minpt2, 0x7F, 4, stream);
        row_norms<<<BN / 4, 256, 0, stream>>>(pool_emb, inv_pn2, BN);
        row_norms<<<BQ / 4, 256, 0, stream>>>(query_emb, inv_qn2, BQ);
        time_min_kernel<<<64, 256, 0, stream>>>(pool_time, minpt2, BN);
        sim_topk_kernel<<<(BQ / QT) * PSPLIT, 512, 0, stream>>>(
            pool_emb, pool_time, query_emb, query_time, inv_pn2, inv_qn2, minpt2, pv, pi);
        finalize_kernel<<<BQ, 64, 0, stream>>>(pool_emb, query_emb, pv, pi, out);
    }
}

// Round 6
// 306.471 us; speedup vs baseline: 5.2141x; 1.1367x over previous
//
#include <hip/hip_runtime.h>
#include <math.h>

#define BQ 2048
#define BN 65536
#define HDIM 256
#define TOPK 7

// ---- new-path geometry ----
#define PB 128               // pool rows per block
#define NPB (BN / PB)        // 512 blocks
#define QI 256               // queries per qi-iteration
#define NQI (BQ / QI)        // 8
#define NFIN 12              // finalists rescored exactly

// ---- old-path geometry (fallback) ----
#define PSPLIT 8
#define QT 32
#define NT 256
#define NTILES (BN / PSPLIT / NT)

typedef unsigned short u16;
using bf16x8 = __attribute__((ext_vector_type(8))) short;
using f32x16 = __attribute__((ext_vector_type(16))) float;

__device__ __forceinline__ bool lexgt(float v1, int i1, float v2, int i2) {
    // (v1,i1) strictly ahead of (v2,i2): value desc, index asc
    return (v1 > v2) || (v1 == v2 && i1 < i2);
}

__device__ __forceinline__ u16 f2bf(float f) {
    unsigned u = __float_as_uint(f);
    unsigned r = (u + 0x7fffu + ((u >> 16) & 1u)) >> 16;
    return (u16)r;
}

// branchless compare-exchange, descending (a keeps max)
#define CEU(a, b) { unsigned _hi = max(a, b), _lo = min(a, b); a = _hi; b = _lo; }

// ================= fused prep: pool norms + time-min | query norms + B-fragments ===========
// blocks [0, BN/16): pool side, 16 rows each (4 waves x 4 rows)
// blocks [BN/16, BN/16+BQ/8): query side, 8 queries each (32 threads per query)
__global__ __launch_bounds__(256) void prep_kernel(
    const float* __restrict__ pool_emb, const float* __restrict__ pool_time,
    const float* __restrict__ query_emb,
    float* __restrict__ inv_pn, float* __restrict__ inv_qn,
    unsigned* __restrict__ minpt, u16* __restrict__ qfrag) {
    const int b = blockIdx.x;
    const int tid = threadIdx.x;
    if (b < BN / 16) {
        const int w = tid >> 6, lane = tid & 63;
        #pragma unroll
        for (int i = 0; i < 4; ++i) {
            int row = b * 16 + w * 4 + i;
            float4 v = *(const float4*)&pool_emb[(size_t)row * HDIM + lane * 4];
            float s = v.x * v.x + v.y * v.y + v.z * v.z + v.w * v.w;
            #pragma unroll
            for (int off = 32; off >= 1; off >>= 1) s += __shfl_xor(s, off);
            if (lane == 0) inv_pn[row] = 1.0f / fmaxf(sqrtf(s), 1e-12f);
        }
        if (tid < 16) {
            float t = pool_time[b * 16 + tid];
            #pragma unroll
            for (int off = 8; off >= 1; off >>= 1) t = fminf(t, __shfl_xor(t, off));
            if (tid == 0) atomicMin(minpt, __float_as_uint(t));  // nonneg: uint order == float order
        }
    } else {
        const int qb = b - BN / 16;
        const int q = qb * 8 + (tid >> 5);
        const int kg = tid & 31;
        const float* src = &query_emb[(size_t)q * HDIM + kg * 8];
        float4 x = *(const float4*)&src[0];
        float4 y = *(const float4*)&src[4];
        float s = x.x * x.x + x.y * x.y + x.z * x.z + x.w * x.w
                + y.x * y.x + y.y * y.y + y.z * y.z + y.w * y.w;
        #pragma unroll
        for (int off = 16; off >= 1; off >>= 1) s += __shfl_xor(s, off);  // 32-thread group reduce
        float iqn = 1.0f / fmaxf(sqrtf(s), 1e-12f);
        if (kg == 0) inv_qn[q] = iqn;
        uint4 u;
        u.x = (unsigned)f2bf(x.x * iqn) | ((unsigned)f2bf(x.y * iqn) << 16);
        u.y = (unsigned)f2bf(x.z * iqn) | ((unsigned)f2bf(x.w * iqn) << 16);
        u.z = (unsigned)f2bf(y.x * iqn) | ((unsigned)f2bf(y.y * iqn) << 16);
        u.w = (unsigned)f2bf(y.z * iqn) | ((unsigned)f2bf(y.w * iqn) << 16);
        unsigned idx = (unsigned)(q >> 5) * 8192u + (unsigned)(kg >> 1) * 512u
                     + ((unsigned)((kg & 1) << 5) + (unsigned)(q & 31)) * 8u;
        *(uint4*)&qfrag[idx] = u;
    }
}

// ================= main: bf16 MFMA sims + branchless packed-key top-4 =================
// 8 waves: pw = w>>2 (2 p-halves of 64 rows), qw = w&3 (4 q-quarters of 64).
// P in LDS (A-fragment order); Q streamed from global fragment order (L2). No barriers in K-loop.
// Selection key: u32 = (bits(val_surr + 2.0) & ~127) | (127 - pl); key 0 = empty/masked.
// val_surr = a * (1 - 0.1*|dt|)  (<=0.54% rel. slip vs exp; exact rescore in finalize).
__global__ __launch_bounds__(512, 4) void sim_topk_mfma3(
    const float* __restrict__ pool_emb,
    const u16* __restrict__ qfrag,
    const float* __restrict__ pool_time,
    const float* __restrict__ query_time,
    const float* __restrict__ inv_pn,
    const unsigned* __restrict__ minpt,
    float4* __restrict__ cand) {
    __shared__ __align__(16) u16 Plds[PB * HDIM];     // 64 KB, A-fragment layout
    __shared__ float tp_s[PB];                        // 512 B
    __shared__ __align__(16) uint4 cand_s[QI];        // 4 KB (pw0 keys)

    const int tid = threadIdx.x;
    const int l = tid & 63;
    const int w = tid >> 6;
    const int pw = w >> 2;       // 0..1
    const int qw = w & 3;        // 0..3
    const int l31 = l & 31;
    const int lhi = l >> 5;      // 0..1
    const int p_base = blockIdx.x * PB;

    // ---- prologue: stage 128 pool rows, normalized bf16, A-fragment layout ----
    {
        const int r = tid >> 2;     // 0..127
        const int c = tid & 3;      // quarter of the row
        const float ipn = inv_pn[p_base + r];
        const float* src = &pool_emb[(size_t)(p_base + r) * HDIM + c * 64];
        const int slab = r >> 5;
        #pragma unroll
        for (int j2 = 0; j2 < 8; ++j2) {
            float4 x = *(const float4*)&src[j2 * 8];
            float4 y = *(const float4*)&src[j2 * 8 + 4];
            uint4 u;
            u.x = (unsigned)f2bf(x.x * ipn) | ((unsigned)f2bf(x.y * ipn) << 16);
            u.y = (unsigned)f2bf(x.z * ipn) | ((unsigned)f2bf(x.w * ipn) << 16);
            u.z = (unsigned)f2bf(y.x * ipn) | ((unsigned)f2bf(y.y * ipn) << 16);
            u.w = (unsigned)f2bf(y.z * ipn) | ((unsigned)f2bf(y.w * ipn) << 16);
            int kg = c * 8 + j2;
            int kt = kg >> 1;
            int lane = ((kg & 1) << 5) | (r & 31);
            *(uint4*)&Plds[slab * 8192 + kt * 512 + lane * 8] = u;
        }
        if (tid < PB) tp_s[tid] = pool_time[p_base + tid];
    }
    __syncthreads();

    const float mpt = __uint_as_float(*minpt);
    const u16* Pbase = &Plds[pw * 16384 + l * 8];
    const unsigned idxb0 = 127u - (unsigned)(pw * 64) - (unsigned)(4 * lhi);

    for (int qi = 0; qi < NQI; ++qi) {
        const int q0 = qi * QI;
        const int slabB = (qi * 4 + qw) * 2;
        const u16* qb0 = &qfrag[(size_t)slabB * 8192 + l * 8];
        const u16* qb1 = &qfrag[(size_t)(slabB + 1) * 8192 + l * 8];

        f32x16 acc[2][2];
        #pragma unroll
        for (int mt = 0; mt < 2; ++mt)
            #pragma unroll
            for (int nt = 0; nt < 2; ++nt)
                #pragma unroll
                for (int v = 0; v < 16; ++v) acc[mt][nt][v] = 0.0f;

        // ---- K-loop: no barriers; reg-double-buffered A (LDS) and B (global/L2)
        bf16x8 b0c = *(const bf16x8*)qb0;
        bf16x8 b1c = *(const bf16x8*)qb1;
        bf16x8 a0c = *(const bf16x8*)(Pbase);
        bf16x8 a1c = *(const bf16x8*)(Pbase + 8192);
        #pragma unroll
        for (int kt = 0; kt < 16; ++kt) {
            bf16x8 b0n = b0c, b1n = b1c, a0n = a0c, a1n = a1c;
            if (kt < 15) {
                b0n = *(const bf16x8*)(qb0 + (kt + 1) * 512);
                b1n = *(const bf16x8*)(qb1 + (kt + 1) * 512);
                a0n = *(const bf16x8*)(Pbase + (kt + 1) * 512);
                a1n = *(const bf16x8*)(Pbase + 8192 + (kt + 1) * 512);
            }
            acc[0][0] = __builtin_amdgcn_mfma_f32_32x32x16_bf16(a0c, b0c, acc[0][0], 0, 0, 0);
            acc[0][1] = __builtin_amdgcn_mfma_f32_32x32x16_bf16(a0c, b1c, acc[0][1], 0, 0, 0);
            acc[1][0] = __builtin_amdgcn_mfma_f32_32x32x16_bf16(a1c, b0c, acc[1][0], 0, 0, 0);
            acc[1][1] = __builtin_amdgcn_mfma_f32_32x32x16_bf16(a1c, b1c, acc[1][1], 0, 0, 0);
            b0c = b0n; b1c = b1n; a0c = a0n; a1c = a1n;
        }

        // ---- epilogue: branchless masked-surrogate packed-key top-4 per q ----
        float tqv[2], tqe[2];
        unsigned L[2][4];
        #pragma unroll
        for (int nt = 0; nt < 2; ++nt) {
            int qq = q0 + qw * 64 + nt * 32 + l31;
            tqv[nt] = query_time[qq];
            tqe[nt] = (mpt < tqv[nt]) ? tqv[nt] : INFINITY;   // mask iff tp >= tqe
            L[nt][0] = 0u; L[nt][1] = 0u; L[nt][2] = 0u; L[nt][3] = 0u;
        }
        #pragma unroll
        for (int mt = 0; mt < 2; ++mt) {
            #pragma unroll
            for (int v = 0; v < 16; ++v) {
                const int rofs = (v & 3) + 8 * (v >> 2);
                float tp = tp_s[pw * 64 + mt * 32 + rofs + 4 * lhi];
                unsigned idxc = idxb0 - (unsigned)(mt * 32 + rofs);
                #pragma unroll
                for (int nt = 0; nt < 2; ++nt) {
                    float a = acc[mt][nt][v];
                    float ad = fabsf(tqv[nt] - tp);
                    float c = fmaf(ad, -0.1f, 1.0f);      // 1 - 0.1|dt|
                    float v2 = fmaf(a, c, 2.0f);          // surrogate val + 2 (positive)
                    unsigned k = (__float_as_uint(v2) & 0xFFFFFF80u) | idxc;
                    k = (tp >= tqe[nt]) ? 0u : k;
                    unsigned c1 = min(L[nt][0], k); L[nt][0] = max(L[nt][0], k);
                    unsigned c2 = min(L[nt][1], c1); L[nt][1] = max(L[nt][1], c1);
                    unsigned c3 = min(L[nt][2], c2); L[nt][2] = max(L[nt][2], c2);
                    L[nt][3] = max(L[nt][3], c3);
                }
            }
        }
        // lane-pair (l, l^32) merge: both interleaved row-halves of this wave's 64 p-rows
        #pragma unroll
        for (int nt = 0; nt < 2; ++nt) {
            unsigned W[4];
            #pragma unroll
            for (int s = 0; s < 4; ++s) W[s] = (unsigned)__shfl_xor((int)L[nt][s], 32);
            unsigned m0 = max(L[nt][0], W[3]);
            unsigned m1 = max(L[nt][1], W[2]);
            unsigned m2 = max(L[nt][2], W[1]);
            unsigned m3 = max(L[nt][3], W[0]);
            CEU(m0, m2); CEU(m1, m3); CEU(m0, m1); CEU(m2, m3); CEU(m1, m2);
            L[nt][0] = m0; L[nt][1] = m1; L[nt][2] = m2; L[nt][3] = m3;
        }
        if (pw == 0 && l < 32) {
            #pragma unroll
            for (int nt = 0; nt < 2; ++nt) {
                int qrow = qw * 64 + nt * 32 + l;
                cand_s[qrow] = make_uint4(L[nt][0], L[nt][1], L[nt][2], L[nt][3]);
            }
        }
        __syncthreads();
        if (pw == 1 && l < 32) {
            #pragma unroll
            for (int nt = 0; nt < 2; ++nt) {
                int qrow = qw * 64 + nt * 32 + l;
                uint4 y = cand_s[qrow];
                unsigned m0 = max(L[nt][0], y.w);
                unsigned m1 = max(L[nt][1], y.z);
                unsigned m2 = max(L[nt][2], y.y);
                unsigned m3 = max(L[nt][3], y.x);
                CEU(m0, m2); CEU(m1, m3); CEU(m0, m1); CEU(m2, m3); CEU(m1, m2);
                unsigned F[4] = {m0, m1, m2, m3};
                float fv[4]; int fi[4];
                #pragma unroll
                for (int s = 0; s < 4; ++s) {
                    unsigned k = F[s];
                    fv[s] = __uint_as_float(k & 0xFFFFFF80u) - 2.0f;
                    fi[s] = p_base + 127 - (int)(k & 127u);
                    if (k == 0u) { fv[s] = -INFINITY; fi[s] = 0x7fffffff; }
                }
                size_t o = ((size_t)(q0 + qrow) * NPB + blockIdx.x) * 2;
                cand[o]     = make_float4(fv[0], __int_as_float(fi[0]), fv[1], __int_as_float(fi[1]));
                cand[o + 1] = make_float4(fv[2], __int_as_float(fi[2]), fv[3], __int_as_float(fi[3]));
            }
        }
        __syncthreads();
    }
}

// ================= finalize v2: 256 threads, parallel merge + exact rescore =================
__global__ __launch_bounds__(256) void finalize2(
    const float* __restrict__ pool_emb, const float* __restrict__ query_emb,
    const float* __restrict__ pool_time, const float* __restrict__ query_time,
    const float* __restrict__ inv_pn, const float* __restrict__ inv_qn,
    const unsigned* __restrict__ minpt,
    const float4* __restrict__ cand,
    float* __restrict__ out) {
    __shared__ float2 wred[NFIN][4];
    __shared__ float exv2[NFIN];
    __shared__ int   exi[NFIN];
    __shared__ float ared[4][TOPK + 1];
    __shared__ float sred[4][4];

    const int q = blockIdx.x;
    const int tid = threadIdx.x;
    const int w = tid >> 6, lane = tid & 63;
    const float tq = query_time[q];
    const bool hv = (__uint_as_float(*minpt) < tq);
    const float iqn = inv_qn[q];

    // phase 1: load 8 approx candidates per thread (coalesced)
    float Sv[8]; int Si[8];
    const float4* base = &cand[(size_t)q * (NPB * 2)];
    #pragma unroll
    for (int j = 0; j < 4; ++j) {
        float4 e = base[j * 256 + tid];
        Sv[2 * j]     = e.x; Si[2 * j]     = __float_as_int(e.y);
        Sv[2 * j + 1] = e.z; Si[2 * j + 1] = __float_as_int(e.w);
    }

    // phase 2: NFIN global argmax-extraction rounds (approx order)
    #pragma unroll 1
    for (int r = 0; r < NFIN; ++r) {
        float bv = Sv[0]; int bi = Si[0];
        #pragma unroll
        for (int s = 1; s < 8; ++s)
            if (lexgt(Sv[s], Si[s], bv, bi)) { bv = Sv[s]; bi = Si[s]; }
        #pragma unroll
        for (int off = 32; off >= 1; off >>= 1) {
            float ov = __shfl_xor(bv, off); int oi = __shfl_xor(bi, off);
            if (lexgt(ov, oi, bv, bi)) { bv = ov; bi = oi; }
        }
        if (lane == 0) wred[r][w] = make_float2(bv, __int_as_float(bi));
        __syncthreads();
        float cv = -INFINITY; int ci = 0x7fffffff;
        #pragma unroll
        for (int ww = 0; ww < 4; ++ww) {
            float2 e = wred[r][ww];
            int ei = __float_as_int(e.y);
            if (lexgt(e.x, ei, cv, ci)) { cv = e.x; ci = ei; }
        }
        if (tid == 0) exi[r] = ci;
        #pragma unroll
        for (int s = 0; s < 8; ++s)
            if (Si[s] == ci) { Sv[s] = -INFINITY; Si[s] = 0x7fffffff; }
    }
    __syncthreads();

    // phase 3: exact fp32 rescore of NFIN finalists (wave w does k = w, w+4, w+8)
    const float4 qv4 = *(const float4*)&query_emb[(size_t)q * HDIM + lane * 4];
    #pragma unroll
    for (int j = 0; j < NFIN / 4; ++j) {
        int k = w + 4 * j;
        int ix = exi[k];
        float vex = -INFINITY;
        if (ix >= 0 && ix < BN) {
            float4 pe = *(const float4*)&pool_emb[(size_t)ix * HDIM + lane * 4];
            float d = qv4.x * pe.x + qv4.y * pe.y + qv4.z * pe.z + qv4.w * pe.w;
            #pragma unroll
            for (int off = 32; off >= 1; off >>= 1) d += __shfl_xor(d, off);
            float tp = pool_time[ix];
            float sim = d * (iqn * inv_pn[ix]) * expf(-0.1f * fabsf(tq - tp));
            vex = (hv && !(tp < tq)) ? -INFINITY : sim;
        }
        if (lane == 0) exv2[k] = vex;
    }
    __syncthreads();

    // phase 4: exact top-7 of NFIN (computed redundantly/uniformly by all threads)
    float E[NFIN]; int EI[NFIN];
    #pragma unroll
    for (int s = 0; s < NFIN; ++s) { E[s] = exv2[s]; EI[s] = exi[s]; }
    int ri[TOPK]; int z = 0;
    #pragma unroll
    for (int k2 = 0; k2 < TOPK; ++k2) {
        float bv = E[0]; int bi = EI[0]; int bs = 0;
        #pragma unroll
        for (int s = 1; s < NFIN; ++s)
            if (lexgt(E[s], EI[s], bv, bi)) { bv = E[s]; bi = EI[s]; bs = s; }
        #pragma unroll
        for (int s = 0; s < NFIN; ++s)
            if (s == bs) E[s] = -INFINITY;
        if (bv == -INFINITY) { ri[k2] = z; z++; }  // ref -inf fallback: indices 0,1,2,...
        else ri[k2] = bi;
    }

    // phase 5: cross-attention fusion + deviation score; thread t = dim t
    const float qd = query_emb[(size_t)q * HDIM + tid];
    float rkd[TOPK], part[TOPK];
    #pragma unroll
    for (int k2 = 0; k2 < TOPK; ++k2) {
        rkd[k2] = pool_emb[(size_t)ri[k2] * HDIM + tid];
        part[k2] = qd * rkd[k2];
    }
    #pragma unroll
    for (int k2 = 0; k2 < TOPK; ++k2) {
        float x = part[k2];
        #pragma unroll
        for (int off = 32; off >= 1; off >>= 1) x += __shfl_xor(x, off);
        part[k2] = x;
    }
    if (lane == 0) {
        #pragma unroll
        for (int k2 = 0; k2 < TOPK; ++k2) ared[w][k2] = part[k2];
    }
    __syncthreads();
    float lg[TOPK];
    #pragma unroll
    for (int k2 = 0; k2 < TOPK; ++k2)
        lg[k2] = (ared[0][k2] + ared[1][k2] + ared[2][k2] + ared[3][k2]) * 0.0625f;
    float m = lg[0];
    #pragma unroll
    for (int k2 = 1; k2 < TOPK; ++k2) m = fmaxf(m, lg[k2]);
    float ee[TOPK], se = 0.0f;
    #pragma unroll
    for (int k2 = 0; k2 < TOPK; ++k2) { ee[k2] = expf(lg[k2] - m); se += ee[k2]; }
    float inv_se = 1.0f / se;
    float f = 0.0f;
    #pragma unroll
    for (int k2 = 0; k2 < TOPK; ++k2) f += ee[k2] * inv_se * rkd[k2];
    float p0 = qd * f, p1 = qd * qd, p2 = f * f;
    float dd = qd - f, p3 = dd * dd;
    #pragma unroll
    for (int off = 32; off >= 1; off >>= 1) {
        p0 += __shfl_xor(p0, off);
        p1 += __shfl_xor(p1, off);
        p2 += __shfl_xor(p2, off);
        p3 += __shfl_xor(p3, off);
    }
    if (lane == 0) { sred[w][0] = p0; sred[w][1] = p1; sred[w][2] = p2; sred[w][3] = p3; }
    __syncthreads();
    if (tid == 0) {
        float dqf = sred[0][0] + sred[1][0] + sred[2][0] + sred[3][0];
        float nq  = sred[0][1] + sred[1][1] + sred[2][1] + sred[3][1];
        float nf  = sred[0][2] + sred[1][2] + sred[2][2] + sred[3][2];
        float d2  = sred[0][3] + sred[1][3] + sred[2][3] + sred[3][3];
        float cosv = dqf / fmaxf(sqrtf(nq) * sqrtf(nf), 1e-8f);
        out[q] = 0.5f * (1.0f - cosv) + 0.5f * sqrtf(d2);
    }
}

// ================= fallback path (round-1 fp32 kernels) =================
__global__ void row_norms(const float* __restrict__ x, float* __restrict__ inv, int rows) {
    int wid = threadIdx.x >> 6, lane = threadIdx.x & 63;
    int row = blockIdx.x * 4 + wid;
    if (row >= rows) return;
    float4 v = *(const float4*)&x[(size_t)row * HDIM + lane * 4];
    float s = v.x * v.x + v.y * v.y + v.z * v.z + v.w * v.w;
    #pragma unroll
    for (int off = 32; off >= 1; off >>= 1) s += __shfl_xor(s, off);
    if (lane == 0) inv[row] = 1.0f / fmaxf(sqrtf(s), 1e-12f);
}

__global__ void time_min_kernel(const float* __restrict__ t, unsigned* __restrict__ m, int n) {
    float mn = 3.0e38f;
    for (int i = blockIdx.x * blockDim.x + threadIdx.x; i < n; i += gridDim.x * blockDim.x)
        mn = fminf(mn, t[i]);
    #pragma unroll
    for (int off = 32; off >= 1; off >>= 1) mn = fminf(mn, __shfl_xor(mn, off));
    __shared__ float wmin[4];
    int wid = threadIdx.x >> 6, lane = threadIdx.x & 63;
    if (lane == 0) wmin[wid] = mn;
    __syncthreads();
    if (threadIdx.x == 0) {
        float b = fminf(fminf(wmin[0], wmin[1]), fminf(wmin[2], wmin[3]));
        atomicMin(m, __float_as_uint(b));
    }
}

#define PPAD 20
__global__ __launch_bounds__(512, 2) void sim_topk_kernel(
    const float* __restrict__ pool_emb, const float* __restrict__ pool_time,
    const float* __restrict__ query_emb, const float* __restrict__ query_time,
    const float* __restrict__ inv_pn, const float* __restrict__ inv_qn,
    const unsigned* __restrict__ minpt,
    float* __restrict__ pv, int* __restrict__ pi) {
    __shared__ __align__(16) float q_s[QT][HDIM];
    __shared__ __align__(16) float p_s[2][NT][PPAD];
    const int tid = threadIdx.x;
    const int ty = tid >> 6;
    const int tx = tid & 63;
    const int split = blockIdx.x & 7;
    const int qb = blockIdx.x >> 3;
    const int qbase = qb * QT;
    #pragma unroll
    for (int k = 0; k < 4; ++k) {
        int c = tid + k * 512;
        int row = c >> 6;
        int col = (c & 63) << 2;
        *(float4*)&q_s[row][col] = *(const float4*)&query_emb[(size_t)(qbase + row) * HDIM + col];
    }
    float tq[4], qiv[4], qep[4], qem[4];
    bool hv[4];
    float tv[4][TOPK];
    int tix[4][TOPK];
    const float mpt = __uint_as_float(*minpt);
    #pragma unroll
    for (int iq = 0; iq < 4; ++iq) {
        int q = qbase + ty * 4 + iq;
        tq[iq] = query_time[q];
        qiv[iq] = inv_qn[q];
        hv[iq] = (mpt < tq[iq]);
        qep[iq] = expf(0.1f * tq[iq]);
        qem[iq] = expf(-0.1f * tq[iq]);
        #pragma unroll
        for (int s = 0; s < TOPK; ++s) { tv[iq][s] = -INFINITY; tix[iq][s] = 0x7fffffff; }
    }
    auto stage = [&](int b, int pb, int hs) {
        #pragma unroll
        for (int k = 0; k < 2; ++k) {
            int c = tid * 2 + k;
            int row = c >> 2;
            int c4 = c & 3;
            *(float4*)&p_s[b][row][c4 * 4] =
                *(const float4*)&pool_emb[(size_t)(pb + row) * HDIM + hs * 16 + c4 * 4];
        }
    };
    for (int t = 0; t < NTILES; ++t) {
        const int pb = split * (BN / PSPLIT) + t * NT;
        float acc[4][4];
        #pragma unroll
        for (int iq = 0; iq < 4; ++iq)
            #pragma unroll
            for (int jp = 0; jp < 4; ++jp) acc[iq][jp] = 0.0f;
        stage(0, pb, 0);
        __syncthreads();
        for (int hs = 0; hs < 16; ++hs) {
            if (hs < 15) stage((hs + 1) & 1, pb, hs + 1);
            const int b = hs & 1;
            #pragma unroll
            for (int c4 = 0; c4 < 4; ++c4) {
                float4 qf[4];
                #pragma unroll
                for (int iq = 0; iq < 4; ++iq)
                    qf[iq] = *(const float4*)&q_s[ty * 4 + iq][hs * 16 + c4 * 4];
                float4 pf[4];
                #pragma unroll
                for (int jp = 0; jp < 4; ++jp)
                    pf[jp] = *(const float4*)&p_s[b][tx + 64 * jp][c4 * 4];
                #pragma unroll
                for (int iq = 0; iq < 4; ++iq) {
                    #pragma unroll
                    for (int jp = 0; jp < 4; ++jp) {
                        acc[iq][jp] += qf[iq].x * pf[jp].x;
                        acc[iq][jp] += qf[iq].y * pf[jp].y;
                        acc[iq][jp] += qf[iq].z * pf[jp].z;
                        acc[iq][jp] += qf[iq].w * pf[jp].w;
                    }
                }
            }
            __syncthreads();
        }
        #pragma unroll
        for (int jp = 0; jp < 4; ++jp) {
            int pj = pb + tx + 64 * jp;
            float tp = pool_time[pj];
            float piv = inv_pn[pj];
            float ep = expf(0.1f * tp), em = expf(-0.1f * tp);
            #pragma unroll
            for (int iq = 0; iq < 4; ++iq) {
                float decay = fminf(qem[iq] * ep, qep[iq] * em);
                float v = acc[iq][jp] * (qiv[iq] * piv) * decay;
                bool causal = tp < tq[iq];
                if (hv[iq] && !causal) v = -INFINITY;
                if (lexgt(v, pj, tv[iq][TOPK - 1], tix[iq][TOPK - 1])) {
                    tv[iq][TOPK - 1] = v; tix[iq][TOPK - 1] = pj;
                    #pragma unroll
                    for (int s = TOPK - 1; s > 0; --s) {
                        if (lexgt(tv[iq][s], tix[iq][s], tv[iq][s - 1], tix[iq][s - 1])) {
                            float fv = tv[iq][s]; tv[iq][s] = tv[iq][s - 1]; tv[iq][s - 1] = fv;
                            int ii = tix[iq][s]; tix[iq][s] = tix[iq][s - 1]; tix[iq][s - 1] = ii;
                        }
                    }
                }
            }
        }
    }
    #define CE(a, b) { if (lexgt(tv[iq][b], tix[iq][b], tv[iq][a], tix[iq][a])) { \
        float fv = tv[iq][a]; tv[iq][a] = tv[iq][b]; tv[iq][b] = fv;              \
        int ii = tix[iq][a]; tix[iq][a] = tix[iq][b]; tix[iq][b] = ii; } }
    #pragma unroll
    for (int off = 1; off < 64; off <<= 1) {
        #pragma unroll
        for (int iq = 0; iq < 4; ++iq) {
            float ov[TOPK]; int oi[TOPK];
            #pragma unroll
            for (int s = 0; s < TOPK; ++s) {
                ov[s] = __shfl_xor(tv[iq][s], off);
                oi[s] = __shfl_xor(tix[iq][s], off);
            }
            #pragma unroll
            for (int i = 0; i < TOPK; ++i) {
                if (lexgt(ov[6 - i], oi[6 - i], tv[iq][i], tix[iq][i])) {
                    tv[iq][i] = ov[6 - i]; tix[iq][i] = oi[6 - i];
                }
            }
            CE(0, 1); CE(2, 3); CE(4, 5);
            CE(0, 2); CE(1, 3); CE(4, 6);
            CE(1, 2); CE(5, 6);
            CE(0, 4); CE(1, 5); CE(2, 6);
            CE(2, 4); CE(3, 5);
            CE(1, 2); CE(3, 4); CE(5, 6);
        }
    }
    #undef CE
    if (tx == 0) {
        #pragma unroll
        for (int iq = 0; iq < 4; ++iq) {
            int q = qbase + ty * 4 + iq;
            #pragma unroll
            for (int s = 0; s < TOPK; ++s) {
                pv[(q * PSPLIT + split) * TOPK + s] = tv[iq][s];
                pi[(q * PSPLIT + split) * TOPK + s] = tix[iq][s];
            }
        }
    }
}

__global__ __launch_bounds__(64) void finalize_kernel(
    const float* __restrict__ pool_emb, const float* __restrict__ query_emb,
    const float* __restrict__ pv, const int* __restrict__ pi,
    float* __restrict__ out) {
    const int q = blockIdx.x;
    const int lane = threadIdx.x;
    float v = -INFINITY; int ix = 0x7fffffff;
    if (lane < PSPLIT * TOPK) {
        v = pv[q * PSPLIT * TOPK + lane];
        ix = pi[q * PSPLIT * TOPK + lane];
    }
    int ri[TOPK];
    #pragma unroll
    for (int k = 0; k < TOPK; ++k) {
        float mv = v; int mi = ix;
        #pragma unroll
        for (int off = 32; off >= 1; off >>= 1) {
            float v2 = __shfl_xor(mv, off);
            int i2 = __shfl_xor(mi, off);
            if (lexgt(v2, i2, mv, mi)) { mv = v2; mi = i2; }
        }
        ri[k] = mi;
        if (ix == mi) { v = -INFINITY; ix = 0x7fffffff; }
    }
    const float4 qv = *(const float4*)&query_emb[(size_t)q * HDIM + lane * 4];
    float4 rk[TOPK];
    float lg[TOPK];
    #pragma unroll
    for (int k = 0; k < TOPK; ++k) {
        int gi = (ri[k] >= 0 && ri[k] < BN) ? ri[k] : 0;
        rk[k] = *(const float4*)&pool_emb[(size_t)gi * HDIM + lane * 4];
        float d = qv.x * rk[k].x + qv.y * rk[k].y + qv.z * rk[k].z + qv.w * rk[k].w;
        #pragma unroll
        for (int off = 32; off >= 1; off >>= 1) d += __shfl_xor(d, off);
        lg[k] = d * 0.0625f;
    }
    float m = lg[0];
    #pragma unroll
    for (int k = 1; k < TOPK; ++k) m = fmaxf(m, lg[k]);
    float e[TOPK], se = 0.0f;
    #pragma unroll
    for (int k = 0; k < TOPK; ++k) { e[k] = expf(lg[k] - m); se += e[k]; }
    float inv_se = 1.0f / se;
    float4 f = make_float4(0.f, 0.f, 0.f, 0.f);
    #pragma unroll
    for (int k = 0; k < TOPK; ++k) {
        float a = e[k] * inv_se;
        f.x += a * rk[k].x; f.y += a * rk[k].y; f.z += a * rk[k].z; f.w += a * rk[k].w;
    }
    float dqf = qv.x * f.x + qv.y * f.y + qv.z * f.z + qv.w * f.w;
    float nq = qv.x * qv.x + qv.y * qv.y + qv.z * qv.z + qv.w * qv.w;
    float nf = f.x * f.x + f.y * f.y + f.z * f.z + f.w * f.w;
    float dx = qv.x - f.x, dy = qv.y - f.y, dz = qv.z - f.z, dw = qv.w - f.w;
    float d2 = dx * dx + dy * dy + dz * dz + dw * dw;
    #pragma unroll
    for (int off = 32; off >= 1; off >>= 1) {
        dqf += __shfl_xor(dqf, off);
        nq += __shfl_xor(nq, off);
        nf += __shfl_xor(nf, off);
        d2 += __shfl_xor(d2, off);
    }
    if (lane == 0) {
        float cosv = dqf / fmaxf(sqrtf(nq) * sqrtf(nf), 1e-8f);
        float l2 = sqrtf(d2);
        out[q] = 0.5f * (1.0f - cosv) + 0.5f * l2;
    }
}

// ================= launch =================
extern "C" void kernel_launch(void* const* d_in, const int* in_sizes, int n_in,
                              void* d_out, int out_size, void* d_ws, size_t ws_size,
                              hipStream_t stream) {
    (void)in_sizes; (void)n_in; (void)out_size;
    const float* query_emb  = (const float*)d_in[0];
    const float* query_time = (const float*)d_in[1];
    const float* pool_emb   = (const float*)d_in[2];
    const float* pool_time  = (const float*)d_in[3];
    float* out = (float*)d_out;

    char* base = (char*)d_ws;
    size_t off = 0;
    auto take = [&](size_t bytes) -> char* {
        off = (off + 255) & ~(size_t)255;
        char* p = base + off;
        off += bytes;
        return p;
    };

    float* inv_pn   = (float*)take((size_t)BN * 4);
    float* inv_qn   = (float*)take((size_t)BQ * 4);
    unsigned* minpt = (unsigned*)take(16);
    u16* qfrag      = (u16*)take((size_t)BQ * HDIM * 2);
    float4* cand    = (float4*)take((size_t)BQ * NPB * 2 * 16);
    bool newpath = (off <= ws_size);

    if (newpath) {
        hipMemsetAsync(minpt, 0x7F, 4, stream);
        prep_kernel<<<BN / 16 + BQ / 8, 256, 0, stream>>>(
            pool_emb, pool_time, query_emb, inv_pn, inv_qn, minpt, qfrag);
        sim_topk_mfma3<<<NPB, 512, 0, stream>>>(
            pool_emb, qfrag, pool_time, query_time, inv_pn, minpt, cand);
        finalize2<<<BQ, 256, 0, stream>>>(pool_emb, query_emb, pool_time, query_time,
                                          inv_pn, inv_qn, minpt, cand, out);
    } else {
        off = 0;
        float* inv_pn2   = (float*)take((size_t)BN * 4);
        float* inv_qn2   = (float*)take((size_t)BQ * 4);
        unsigned* minpt2 = (unsigned*)take(16);
        float* pv = (float*)take((size_t)BQ * PSPLIT * TOPK * 4);
        int* pi   = (int*)take((size_t)BQ * PSPLIT * TOPK * 4);
        hipMemsetAsync(minpt2, 0x7F, 4, stream);
        row_norms<<<BN / 4, 256, 0, stream>>>(pool_emb, inv_pn2, BN);
        row_norms<<<BQ / 4, 256, 0, stream>>>(query_emb, inv_qn2, BQ);
        time_min_kernel<<<64, 256, 0, stream>>>(pool_time, minpt2, BN);
        sim_topk_kernel<<<(BQ / QT) * PSPLIT, 512, 0, stream>>>(
            pool_emb, pool_time, query_emb, query_time, inv_pn2, inv_qn2, minpt2, pv, pi);
        finalize_kernel<<<BQ, 64, 0, stream>>>(pool_emb, query_emb, pv, pi, out);
    }
}